// Round 1
// baseline (973.170 us; speedup 1.0000x reference)
//
#include <hip/hip_runtime.h>
#include <hip/hip_bf16.h>

typedef __bf16 bf16;
typedef __bf16 bf16x8 __attribute__((ext_vector_type(8)));
typedef float f32x4 __attribute__((ext_vector_type(4)));

constexpr int N_NODES  = 100000;
constexpr int N_EDGES  = 800000;
constexpr int N_GRAPHS = 512;
constexpr int D_IN  = 300;
constexpr int D_HID = 300;
constexpr int D_OUT = 128;
constexpr int KP    = 320;   // padded feature stride (multiple of 32 for MFMA K-steps)

#define AS1(p) ((const __attribute__((address_space(1))) void*)(p))
#define AS3(p) ((__attribute__((address_space(3))) void*)(p))

// ---------------- setup kernels ----------------

__global__ __launch_bounds__(256) void k_init(int* deg, float* gsum, int* cnt) {
  int i = blockIdx.x * 256 + threadIdx.x;
  if (i < N_NODES) deg[i] = 0;
  if (i < N_GRAPHS) { gsum[i] = 0.f; cnt[i] = 0; }
}

__global__ __launch_bounds__(256) void k_deg(const int* __restrict__ ei, int* __restrict__ deg) {
  int e = blockIdx.x * 256 + threadIdx.x;
  if (e < N_EDGES) atomicAdd(&deg[ei[N_EDGES + e]], 1);
}

__global__ __launch_bounds__(256) void k_dinv(const int* __restrict__ deg, float* __restrict__ dinv) {
  int v = blockIdx.x * 256 + threadIdx.x;
  if (v < N_NODES) dinv[v] = rsqrtf((float)(deg[v] + 1));  // +1 self loop, deg>=1 always
}

// 3-kernel exclusive scan of deg -> row_ptr
__global__ __launch_bounds__(256) void k_scan1(const int* __restrict__ deg, int* __restrict__ rp,
                                               int* __restrict__ part) {
  __shared__ int sm[256];
  int tid = threadIdx.x;
  int i = blockIdx.x * 256 + tid;
  int v = (i < N_NODES) ? deg[i] : 0;
  sm[tid] = v;
  __syncthreads();
  for (int off = 1; off < 256; off <<= 1) {
    int t = (tid >= off) ? sm[tid - off] : 0;
    __syncthreads();
    sm[tid] += t;
    __syncthreads();
  }
  if (i < N_NODES) rp[i] = sm[tid] - v;       // exclusive
  if (tid == 255) part[blockIdx.x] = sm[255]; // block total
}

__global__ __launch_bounds__(512) void k_scan2(int* part, int nb) {
  __shared__ int sm[512];
  int tid = threadIdx.x;
  int v = (tid < nb) ? part[tid] : 0;
  sm[tid] = v;
  __syncthreads();
  for (int off = 1; off < 512; off <<= 1) {
    int t = (tid >= off) ? sm[tid - off] : 0;
    __syncthreads();
    sm[tid] += t;
    __syncthreads();
  }
  if (tid < nb) part[tid] = sm[tid] - v;      // exclusive block offsets
}

__global__ __launch_bounds__(256) void k_scan3(int* __restrict__ rp, const int* __restrict__ part,
                                               int* __restrict__ cur) {
  int i = blockIdx.x * 256 + threadIdx.x;
  if (i < N_NODES) {
    int r = rp[i] + part[blockIdx.x];
    rp[i] = r;
    cur[i] = r;
  }
  if (i == 0) rp[N_NODES] = N_EDGES;
}

__global__ __launch_bounds__(256) void k_fill(const int* __restrict__ ei, int* __restrict__ cur,
                                              int* __restrict__ col) {
  int e = blockIdx.x * 256 + threadIdx.x;
  if (e < N_EDGES) {
    int s = ei[e];               // src
    int d = ei[N_EDGES + e];     // dst
    int p = atomicAdd(&cur[d], 1);
    col[p] = s;
  }
}

// ---------------- conversions ----------------

__global__ __launch_bounds__(256) void k_conv_x(const float* __restrict__ x, bf16* __restrict__ Xb) {
  int i = blockIdx.x * 256 + threadIdx.x;       // over N_NODES*KP (32M, fits int)
  if (i >= N_NODES * KP) return;
  int k = i % KP;
  int v = i / KP;
  float f = (k < D_IN) ? x[v * D_IN + k] : 0.f;
  Xb[i] = (bf16)f;
}

// Wt[n][k] = W[k][n], zero-padded to [KP][KP]
__global__ __launch_bounds__(256) void k_conv_w(const float* __restrict__ W, bf16* __restrict__ Wt,
                                                int Kin, int Nin) {
  int i = blockIdx.x * 256 + threadIdx.x;       // i = n*KP + k
  if (i >= KP * KP) return;
  int k = i % KP;
  int n = i / KP;
  float f = (k < Kin && n < Nin) ? W[k * Nin + n] : 0.f;
  Wt[i] = (bf16)f;
}

// ---------------- GEMM: T[v][n] = dinv[v] * (A @ Wt^T)[v][n] ----------------
// A: [N_NODES][KP] bf16 row-major (k-contiguous). Bt: [KP][KP] bf16, n-major (k-contiguous).
// Tile 64x64, 4 waves (2x2), each wave 32x32 via 4x mfma_f32_16x16x32_bf16.

__global__ __launch_bounds__(256) void k_gemm(const bf16* __restrict__ A, const bf16* __restrict__ Bt,
                                              const float* __restrict__ dinv, float* __restrict__ T) {
  __shared__ __attribute__((aligned(16))) bf16 sA[64 * 32];
  __shared__ __attribute__((aligned(16))) bf16 sB[64 * 32];
  int m0 = blockIdx.x * 64;
  int n0 = blockIdx.y * 64;
  int tid = threadIdx.x;
  int w = tid >> 6, l = tid & 63;
  int wm = w >> 1, wn = w & 1;

  // staging: wave w stages rows [w*16, w*16+16) of each tile; lane l -> row w*16+(l>>2), 16B chunk (l&3)
  int rA = m0 + w * 16 + (l >> 2);
  if (rA > N_NODES - 1) rA = N_NODES - 1;       // clamp; junk rows masked on store
  const bf16* gA = A + rA * KP + (l & 3) * 8;
  int rB = n0 + w * 16 + (l >> 2);              // always within padded Wt
  const bf16* gB = Bt + rB * KP + (l & 3) * 8;
  bf16* lA = &sA[w * 512];                      // wave-uniform LDS base; HW adds lane*16B
  bf16* lB = &sB[w * 512];

  f32x4 acc[2][2] = {};

  for (int k0 = 0; k0 < KP; k0 += 32) {
    __builtin_amdgcn_global_load_lds(AS1(gA + k0), AS3(lA), 16, 0, 0);
    __builtin_amdgcn_global_load_lds(AS1(gB + k0), AS3(lB), 16, 0, 0);
    __syncthreads();  // drains vmcnt, staging visible to all waves

    int la = l & 15;
    int kk = (l >> 4) * 8;
    bf16x8 a0 = *(const bf16x8*)&sA[(wm * 32 + la) * 32 + kk];
    bf16x8 a1 = *(const bf16x8*)&sA[(wm * 32 + 16 + la) * 32 + kk];
    bf16x8 b0 = *(const bf16x8*)&sB[(wn * 32 + la) * 32 + kk];
    bf16x8 b1 = *(const bf16x8*)&sB[(wn * 32 + 16 + la) * 32 + kk];
    acc[0][0] = __builtin_amdgcn_mfma_f32_16x16x32_bf16(a0, b0, acc[0][0], 0, 0, 0);
    acc[0][1] = __builtin_amdgcn_mfma_f32_16x16x32_bf16(a0, b1, acc[0][1], 0, 0, 0);
    acc[1][0] = __builtin_amdgcn_mfma_f32_16x16x32_bf16(a1, b0, acc[1][0], 0, 0, 0);
    acc[1][1] = __builtin_amdgcn_mfma_f32_16x16x32_bf16(a1, b1, acc[1][1], 0, 0, 0);

    __syncthreads();  // all waves done reading before next overwrite
  }

  // C/D layout (verified): col = lane&15, row = (lane>>4)*4 + reg
  int rbase = m0 + wm * 32 + (l >> 4) * 4;
  int cbase = n0 + wn * 32 + (l & 15);
  for (int mi = 0; mi < 2; ++mi) {
    for (int r = 0; r < 4; ++r) {
      int row = rbase + mi * 16 + r;
      if (row < N_NODES) {
        float dv = dinv[row];
        for (int ni = 0; ni < 2; ++ni)
          T[row * KP + cbase + ni * 16] = acc[mi][ni][r] * dv;
      }
    }
  }
}

// ---------------- aggregation: h[v] = relu(dinv[v]*(sum_nbr T[u] + T[v]) + b) ----------------
// one wave per node

template <bool LAST>
__global__ __launch_bounds__(256) void k_agg(const float* __restrict__ T, const int* __restrict__ rp,
                                             const int* __restrict__ col, const float* __restrict__ dinv,
                                             const float* __restrict__ bias, bf16* __restrict__ outB,
                                             float* __restrict__ outF) {
  int w = threadIdx.x >> 6, l = threadIdx.x & 63;
  int v = blockIdx.x * 4 + w;
  if (v >= N_NODES) return;
  constexpr int D  = LAST ? D_OUT : D_HID;   // 128 or 300
  constexpr int NC = LAST ? 2 : 5;
  float a[NC];
#pragma unroll
  for (int c = 0; c < NC; ++c) a[c] = 0.f;

  int s = rp[v], e = rp[v + 1];
  for (int i = s; i <= e; ++i) {             // e-s neighbors, then self at i==e
    int u = (i < e) ? col[i] : v;
    const float* Tu = T + u * KP;
#pragma unroll
    for (int c = 0; c < NC; ++c) {
      int d = l + 64 * c;
      if (d < D) a[c] += Tu[d];
    }
  }
  float dv = dinv[v];
#pragma unroll
  for (int c = 0; c < NC; ++c) {
    int d = l + 64 * c;
    if (LAST) {
      if (d < D) outF[v * D_OUT + d] = fmaxf(a[c] * dv + bias[d], 0.f);
    } else {
      if (d < KP) {
        float val = (d < D) ? fmaxf(a[c] * dv + bias[d], 0.f) : 0.f;
        outB[v * KP + d] = (bf16)val;        // bf16 for next layer's GEMM; pads zeroed
      }
    }
  }
}

// ---------------- readout: s[v] = h3[v].Wm ; gsum[batch[v]] += s ----------------

__global__ __launch_bounds__(256) void k_dot(const float* __restrict__ h3, const float* __restrict__ Wm,
                                             const int* __restrict__ batch, float* __restrict__ gsum,
                                             int* __restrict__ cnt) {
  int w = threadIdx.x >> 6, l = threadIdx.x & 63;
  int v = blockIdx.x * 4 + w;
  if (v >= N_NODES) return;
  float s = h3[v * D_OUT + l] * Wm[l] + h3[v * D_OUT + 64 + l] * Wm[64 + l];
  for (int off = 32; off > 0; off >>= 1) s += __shfl_down(s, off);
  if (l == 0) {
    atomicAdd(&gsum[batch[v]], s);
    atomicAdd(&cnt[batch[v]], 1);
  }
}

__global__ __launch_bounds__(512) void k_final(const float* __restrict__ gsum, const int* __restrict__ cnt,
                                               const float* __restrict__ bm, float* __restrict__ out) {
  int g = blockIdx.x * 512 + threadIdx.x;
  if (g < N_GRAPHS) out[g] = gsum[g] / fmaxf((float)cnt[g], 1.f) + bm[0];
}

// ---------------- launch ----------------

extern "C" void kernel_launch(void* const* d_in, const int* in_sizes, int n_in,
                              void* d_out, int out_size, void* d_ws, size_t ws_size,
                              hipStream_t stream) {
  const float* x    = (const float*)d_in[0];
  const int*   ei   = (const int*)d_in[1];
  const int*   batch= (const int*)d_in[2];
  const float* W1   = (const float*)d_in[3];
  const float* b1   = (const float*)d_in[4];
  const float* W2   = (const float*)d_in[5];
  const float* b2   = (const float*)d_in[6];
  const float* W3   = (const float*)d_in[7];
  const float* b3   = (const float*)d_in[8];
  const float* Wm   = (const float*)d_in[9];
  const float* bm   = (const float*)d_in[10];
  float* out = (float*)d_out;

  char* ws = (char*)d_ws;
  size_t off = 0;
  auto alloc = [&](size_t bytes) {
    void* p = ws + off;
    off = (off + bytes + 255) & ~(size_t)255;
    return p;
  };
  bf16*  Xb   = (bf16*)alloc((size_t)N_NODES * KP * sizeof(bf16));   // 64 MB
  float* T    = (float*)alloc((size_t)N_NODES * KP * sizeof(float)); // 128 MB
  bf16*  Wt   = (bf16*)alloc((size_t)KP * KP * sizeof(bf16));
  int*   deg  = (int*)alloc((size_t)N_NODES * 4);
  float* dinv = (float*)alloc((size_t)N_NODES * 4);
  int*   rp   = (int*)alloc((size_t)(N_NODES + 1) * 4);
  int*   cur  = (int*)alloc((size_t)N_NODES * 4);
  int*   col  = (int*)alloc((size_t)N_EDGES * 4);
  int*   part = (int*)alloc(512 * 4);
  float* gsum = (float*)alloc((size_t)N_GRAPHS * 4);
  int*   cnt  = (int*)alloc((size_t)N_GRAPHS * 4);
  float* h3   = (float*)Xb;  // reuse Xb region after layer-3 GEMM consumed it

  int nbN = (N_NODES + 255) / 256;   // 391
  int nbE = (N_EDGES + 255) / 256;   // 3125
  int nbA = (N_NODES + 3) / 4;       // 25000 (4 nodes / block)

  k_init<<<nbN, 256, 0, stream>>>(deg, gsum, cnt);
  k_deg<<<nbE, 256, 0, stream>>>(ei, deg);
  k_dinv<<<nbN, 256, 0, stream>>>(deg, dinv);
  k_scan1<<<nbN, 256, 0, stream>>>(deg, rp, part);
  k_scan2<<<1, 512, 0, stream>>>(part, nbN);
  k_scan3<<<nbN, 256, 0, stream>>>(rp, part, cur);
  k_fill<<<nbE, 256, 0, stream>>>(ei, cur, col);
  k_conv_x<<<(N_NODES * KP + 255) / 256, 256, 0, stream>>>(x, Xb);

  dim3 g12((N_NODES + 63) / 64, 5);  // N=320 cols (300 + zero pad)
  dim3 g3((N_NODES + 63) / 64, 2);   // N=128 cols
  int nbW = (KP * KP + 255) / 256;

  // layer 1
  k_conv_w<<<nbW, 256, 0, stream>>>(W1, Wt, 300, 300);
  k_gemm<<<g12, 256, 0, stream>>>(Xb, Wt, dinv, T);
  k_agg<false><<<nbA, 256, 0, stream>>>(T, rp, col, dinv, b1, Xb, nullptr);
  // layer 2
  k_conv_w<<<nbW, 256, 0, stream>>>(W2, Wt, 300, 300);
  k_gemm<<<g12, 256, 0, stream>>>(Xb, Wt, dinv, T);
  k_agg<false><<<nbA, 256, 0, stream>>>(T, rp, col, dinv, b2, Xb, nullptr);
  // layer 3
  k_conv_w<<<nbW, 256, 0, stream>>>(W3, Wt, 300, 128);
  k_gemm<<<g3, 256, 0, stream>>>(Xb, Wt, dinv, T);
  k_agg<true><<<nbA, 256, 0, stream>>>(T, rp, col, dinv, b3, nullptr, h3);

  k_dot<<<nbA, 256, 0, stream>>>(h3, Wm, batch, gsum, cnt);
  k_final<<<1, 512, 0, stream>>>(gsum, cnt, bm, out);
}

// Round 2
// 770.051 us; speedup vs baseline: 1.2638x; 1.2638x over previous
//
#include <hip/hip_runtime.h>
#include <hip/hip_bf16.h>

typedef __bf16 bf16;
typedef __bf16 bf16x4 __attribute__((ext_vector_type(4)));
typedef __bf16 bf16x8 __attribute__((ext_vector_type(8)));
typedef float f32x4 __attribute__((ext_vector_type(4)));

constexpr int N_NODES  = 100000;
constexpr int N_EDGES  = 800000;
constexpr int N_GRAPHS = 512;
constexpr int D_IN  = 300;
constexpr int D_HID = 300;
constexpr int D_OUT = 128;
constexpr int KP    = 320;   // padded feature stride (multiple of 32 for MFMA K-steps)

#define AS1(p) ((const __attribute__((address_space(1))) void*)(p))
#define AS3(p) ((__attribute__((address_space(3))) void*)(p))

// ---------------- setup kernels ----------------

__global__ __launch_bounds__(256) void k_init(int* deg, float* gsum, int* cnt) {
  int i = blockIdx.x * 256 + threadIdx.x;
  if (i < N_NODES) deg[i] = 0;
  if (i < N_GRAPHS) { gsum[i] = 0.f; cnt[i] = 0; }
}

__global__ __launch_bounds__(256) void k_deg(const int* __restrict__ ei, int* __restrict__ deg) {
  int e = blockIdx.x * 256 + threadIdx.x;
  if (e < N_EDGES) atomicAdd(&deg[ei[N_EDGES + e]], 1);
}

__global__ __launch_bounds__(256) void k_dinv(const int* __restrict__ deg, float* __restrict__ dinv) {
  int v = blockIdx.x * 256 + threadIdx.x;
  if (v < N_NODES) dinv[v] = rsqrtf((float)(deg[v] + 1));  // +1 self loop
}

// 3-kernel exclusive scan of deg -> row_ptr
__global__ __launch_bounds__(256) void k_scan1(const int* __restrict__ deg, int* __restrict__ rp,
                                               int* __restrict__ part) {
  __shared__ int sm[256];
  int tid = threadIdx.x;
  int i = blockIdx.x * 256 + tid;
  int v = (i < N_NODES) ? deg[i] : 0;
  sm[tid] = v;
  __syncthreads();
  for (int off = 1; off < 256; off <<= 1) {
    int t = (tid >= off) ? sm[tid - off] : 0;
    __syncthreads();
    sm[tid] += t;
    __syncthreads();
  }
  if (i < N_NODES) rp[i] = sm[tid] - v;       // exclusive
  if (tid == 255) part[blockIdx.x] = sm[255]; // block total
}

__global__ __launch_bounds__(512) void k_scan2(int* part, int nb) {
  __shared__ int sm[512];
  int tid = threadIdx.x;
  int v = (tid < nb) ? part[tid] : 0;
  sm[tid] = v;
  __syncthreads();
  for (int off = 1; off < 512; off <<= 1) {
    int t = (tid >= off) ? sm[tid - off] : 0;
    __syncthreads();
    sm[tid] += t;
    __syncthreads();
  }
  if (tid < nb) part[tid] = sm[tid] - v;      // exclusive block offsets
}

__global__ __launch_bounds__(256) void k_scan3(int* __restrict__ rp, const int* __restrict__ part,
                                               int* __restrict__ cur) {
  int i = blockIdx.x * 256 + threadIdx.x;
  if (i < N_NODES) {
    int r = rp[i] + part[blockIdx.x];
    rp[i] = r;
    cur[i] = r;
  }
  if (i == 0) rp[N_NODES] = N_EDGES;
}

__global__ __launch_bounds__(256) void k_fill(const int* __restrict__ ei, int* __restrict__ cur,
                                              int* __restrict__ col) {
  int e = blockIdx.x * 256 + threadIdx.x;
  if (e < N_EDGES) {
    int s = ei[e];               // src
    int d = ei[N_EDGES + e];     // dst
    int p = atomicAdd(&cur[d], 1);
    col[p] = s;
  }
}

// ---------------- conversions ----------------

// vectorized: thread = (node, 4-col group); float4 load -> bf16x4 store
__global__ __launch_bounds__(256) void k_conv_x(const float* __restrict__ x, bf16* __restrict__ Xb) {
  int i = blockIdx.x * 256 + threadIdx.x;       // over N_NODES*80
  if (i >= N_NODES * (KP / 4)) return;
  int j = i % (KP / 4);
  int v = i / (KP / 4);
  float4 f = make_float4(0.f, 0.f, 0.f, 0.f);
  if (j < D_IN / 4) f = ((const float4*)(x + (size_t)v * D_IN))[j];
  bf16x4 o;
  o[0] = (bf16)f.x; o[1] = (bf16)f.y; o[2] = (bf16)f.z; o[3] = (bf16)f.w;
  *(bf16x4*)(Xb + (size_t)v * KP + j * 4) = o;
}

// Wt[n][k] = W[k][n], zero-padded to [KP][KP]
__global__ __launch_bounds__(256) void k_conv_w(const float* __restrict__ W, bf16* __restrict__ Wt,
                                                int Kin, int Nin) {
  int i = blockIdx.x * 256 + threadIdx.x;       // i = n*KP + k
  if (i >= KP * KP) return;
  int k = i % KP;
  int n = i / KP;
  float f = (k < Kin && n < Nin) ? W[k * Nin + n] : 0.f;
  Wt[i] = (bf16)f;
}

// ---------------- GEMM: T[v][n] = dinv[v] * (A @ Wt^T)[v][n] ----------------
// A: [N_NODES][KP] bf16 row-major. Bt: [KP][KP] bf16, n-major (k-contiguous).
// Tile 64x64, 4 waves (2x2), each wave 32x32 via 4x mfma_f32_16x16x32_bf16.

__global__ __launch_bounds__(256) void k_gemm(const bf16* __restrict__ A, const bf16* __restrict__ Bt,
                                              const float* __restrict__ dinv, float* __restrict__ T) {
  __shared__ __attribute__((aligned(16))) bf16 sA[64 * 32];
  __shared__ __attribute__((aligned(16))) bf16 sB[64 * 32];
  int m0 = blockIdx.x * 64;
  int n0 = blockIdx.y * 64;
  int tid = threadIdx.x;
  int w = tid >> 6, l = tid & 63;
  int wm = w >> 1, wn = w & 1;

  int rA = m0 + w * 16 + (l >> 2);
  if (rA > N_NODES - 1) rA = N_NODES - 1;       // clamp; junk rows masked on store
  const bf16* gA = A + (size_t)rA * KP + (l & 3) * 8;
  int rB = n0 + w * 16 + (l >> 2);
  const bf16* gB = Bt + (size_t)rB * KP + (l & 3) * 8;
  bf16* lA = &sA[w * 512];
  bf16* lB = &sB[w * 512];

  f32x4 acc[2][2] = {};

  for (int k0 = 0; k0 < KP; k0 += 32) {
    __builtin_amdgcn_global_load_lds(AS1(gA + k0), AS3(lA), 16, 0, 0);
    __builtin_amdgcn_global_load_lds(AS1(gB + k0), AS3(lB), 16, 0, 0);
    __syncthreads();

    int la = l & 15;
    int kk = (l >> 4) * 8;
    bf16x8 a0 = *(const bf16x8*)&sA[(wm * 32 + la) * 32 + kk];
    bf16x8 a1 = *(const bf16x8*)&sA[(wm * 32 + 16 + la) * 32 + kk];
    bf16x8 b0 = *(const bf16x8*)&sB[(wn * 32 + la) * 32 + kk];
    bf16x8 b1 = *(const bf16x8*)&sB[(wn * 32 + 16 + la) * 32 + kk];
    acc[0][0] = __builtin_amdgcn_mfma_f32_16x16x32_bf16(a0, b0, acc[0][0], 0, 0, 0);
    acc[0][1] = __builtin_amdgcn_mfma_f32_16x16x32_bf16(a0, b1, acc[0][1], 0, 0, 0);
    acc[1][0] = __builtin_amdgcn_mfma_f32_16x16x32_bf16(a1, b0, acc[1][0], 0, 0, 0);
    acc[1][1] = __builtin_amdgcn_mfma_f32_16x16x32_bf16(a1, b1, acc[1][1], 0, 0, 0);

    __syncthreads();
  }

  // C/D layout: col = lane&15, row = (lane>>4)*4 + reg
  int rbase = m0 + wm * 32 + (l >> 4) * 4;
  int cbase = n0 + wn * 32 + (l & 15);
  for (int mi = 0; mi < 2; ++mi) {
    for (int r = 0; r < 4; ++r) {
      int row = rbase + mi * 16 + r;
      if (row < N_NODES) {
        float dv = dinv[row];
        for (int ni = 0; ni < 2; ++ni)
          T[(size_t)row * KP + cbase + ni * 16] = acc[mi][ni][r] * dv;
      }
    }
  }
}

// ---------------- aggregation: h[v] = relu(dinv[v]*(sum_nbr T[u] + T[v]) + b) ----------------
// one wave per node; LAST layer fuses the Wm dot -> sArr[v] (no h3 materialization)

template <bool LAST>
__global__ __launch_bounds__(256) void k_agg(const float* __restrict__ T, const int* __restrict__ rp,
                                             const int* __restrict__ col, const float* __restrict__ dinv,
                                             const float* __restrict__ bias, bf16* __restrict__ outB,
                                             const float* __restrict__ Wm, float* __restrict__ sArr) {
  int w = threadIdx.x >> 6, l = threadIdx.x & 63;
  int v = blockIdx.x * 4 + w;
  if (v >= N_NODES) return;
  constexpr int D  = LAST ? D_OUT : D_HID;   // 128 or 300
  constexpr int NC = LAST ? 2 : 5;
  float a[NC];
#pragma unroll
  for (int c = 0; c < NC; ++c) a[c] = 0.f;

  int s = rp[v], e = rp[v + 1];
  for (int i = s; i <= e; ++i) {             // neighbors, then self at i==e
    int u = (i < e) ? col[i] : v;
    const float* Tu = T + (size_t)u * KP;
#pragma unroll
    for (int c = 0; c < NC; ++c) {
      int d = l + 64 * c;
      if (d < D) a[c] += Tu[d];
    }
  }
  float dv = dinv[v];
  if (LAST) {
    float sv = 0.f;
#pragma unroll
    for (int c = 0; c < NC; ++c) {
      int d = l + 64 * c;
      float val = fmaxf(a[c] * dv + bias[d], 0.f);
      sv += val * Wm[d];
    }
    for (int off = 32; off > 0; off >>= 1) sv += __shfl_down(sv, off);
    if (l == 0) sArr[v] = sv;
  } else {
#pragma unroll
    for (int c = 0; c < NC; ++c) {
      int d = l + 64 * c;
      if (d < KP) {
        float val = (d < D) ? fmaxf(a[c] * dv + bias[d], 0.f) : 0.f;
        outB[(size_t)v * KP + d] = (bf16)val;  // bf16 for next GEMM; pads zeroed
      }
    }
  }
}

// ---------------- pooled reduction: LDS histogram per block, sparse flush ----------------

__global__ __launch_bounds__(256) void k_gsum(const float* __restrict__ sArr, const int* __restrict__ batch,
                                              float* __restrict__ gsum, int* __restrict__ cnt) {
  __shared__ float lsum[N_GRAPHS];
  __shared__ int   lcnt[N_GRAPHS];
  int tid = threadIdx.x;
  lsum[tid] = 0.f; lsum[tid + 256] = 0.f;
  lcnt[tid] = 0;   lcnt[tid + 256] = 0;
  __syncthreads();
  int v = blockIdx.x * 256 + tid;
  if (v < N_NODES) {
    int b = batch[v];
    atomicAdd(&lsum[b], sArr[v]);
    atomicAdd(&lcnt[b], 1);
  }
  __syncthreads();
  // sorted batch -> only ~2-3 nonzero slots per block; flush those only
  for (int g = tid; g < N_GRAPHS; g += 256) {
    int c = lcnt[g];
    if (c) { atomicAdd(&gsum[g], lsum[g]); atomicAdd(&cnt[g], c); }
  }
}

__global__ __launch_bounds__(512) void k_final(const float* __restrict__ gsum, const int* __restrict__ cnt,
                                               const float* __restrict__ bm, float* __restrict__ out) {
  int g = blockIdx.x * 512 + threadIdx.x;
  if (g < N_GRAPHS) out[g] = gsum[g] / fmaxf((float)cnt[g], 1.f) + bm[0];
}

// ---------------- launch ----------------

extern "C" void kernel_launch(void* const* d_in, const int* in_sizes, int n_in,
                              void* d_out, int out_size, void* d_ws, size_t ws_size,
                              hipStream_t stream) {
  const float* x    = (const float*)d_in[0];
  const int*   ei   = (const int*)d_in[1];
  const int*   batch= (const int*)d_in[2];
  const float* W1   = (const float*)d_in[3];
  const float* b1   = (const float*)d_in[4];
  const float* W2   = (const float*)d_in[5];
  const float* b2   = (const float*)d_in[6];
  const float* W3   = (const float*)d_in[7];
  const float* b3   = (const float*)d_in[8];
  const float* Wm   = (const float*)d_in[9];
  const float* bm   = (const float*)d_in[10];
  float* out = (float*)d_out;

  char* ws = (char*)d_ws;
  size_t off = 0;
  auto alloc = [&](size_t bytes) {
    void* p = ws + off;
    off = (off + bytes + 255) & ~(size_t)255;
    return p;
  };
  bf16*  Xb   = (bf16*)alloc((size_t)N_NODES * KP * sizeof(bf16));   // 64 MB
  float* T    = (float*)alloc((size_t)N_NODES * KP * sizeof(float)); // 128 MB
  bf16*  Wt   = (bf16*)alloc((size_t)KP * KP * sizeof(bf16));
  int*   deg  = (int*)alloc((size_t)N_NODES * 4);
  float* dinv = (float*)alloc((size_t)N_NODES * 4);
  int*   rp   = (int*)alloc((size_t)(N_NODES + 1) * 4);
  int*   cur  = (int*)alloc((size_t)N_NODES * 4);
  int*   col  = (int*)alloc((size_t)N_EDGES * 4);
  float* sArr = (float*)alloc((size_t)N_NODES * 4);
  float* gsum = (float*)alloc((size_t)N_GRAPHS * 4);
  int*   cnt  = (int*)alloc((size_t)N_GRAPHS * 4);

  int nbN = (N_NODES + 255) / 256;   // 391
  int nbE = (N_EDGES + 255) / 256;   // 3125
  int nbA = (N_NODES + 3) / 4;       // 25000 (4 nodes / block)

  k_init<<<nbN, 256, 0, stream>>>(deg, gsum, cnt);
  k_deg<<<nbE, 256, 0, stream>>>(ei, deg);
  k_dinv<<<nbN, 256, 0, stream>>>(deg, dinv);
  k_scan1<<<nbN, 256, 0, stream>>>(deg, rp, (int*)cur);  // reuse cur as part buffer? no — keep separate
  // NOTE: part buffer must be distinct; use tail of ws
  // (re-dispatch with proper buffer below)
  k_scan2<<<1, 512, 0, stream>>>((int*)cur, nbN);
  k_scan3<<<nbN, 256, 0, stream>>>(rp, (int*)cur, cur);  // overwritten below anyway

  // The above reuse is wrong; do it cleanly with a dedicated part buffer:
  // (kept simple: allocate and redo the scan properly)
  {
    int* part = (int*)alloc(1024 * 4);
    k_scan1<<<nbN, 256, 0, stream>>>(deg, rp, part);
    k_scan2<<<1, 512, 0, stream>>>(part, nbN);
    k_scan3<<<nbN, 256, 0, stream>>>(rp, part, cur);
  }
  k_fill<<<nbE, 256, 0, stream>>>(ei, cur, col);
  k_conv_x<<<(N_NODES * (KP / 4) + 255) / 256, 256, 0, stream>>>(x, Xb);

  dim3 g12((N_NODES + 63) / 64, 5);  // N=320 cols (300 + zero pad)
  dim3 g3((N_NODES + 63) / 64, 2);   // N=128 cols
  int nbW = (KP * KP + 255) / 256;

  // layer 1
  k_conv_w<<<nbW, 256, 0, stream>>>(W1, Wt, 300, 300);
  k_gemm<<<g12, 256, 0, stream>>>(Xb, Wt, dinv, T);
  k_agg<false><<<nbA, 256, 0, stream>>>(T, rp, col, dinv, b1, Xb, nullptr, nullptr);
  // layer 2
  k_conv_w<<<nbW, 256, 0, stream>>>(W2, Wt, 300, 300);
  k_gemm<<<g12, 256, 0, stream>>>(Xb, Wt, dinv, T);
  k_agg<false><<<nbA, 256, 0, stream>>>(T, rp, col, dinv, b2, Xb, nullptr, nullptr);
  // layer 3
  k_conv_w<<<nbW, 256, 0, stream>>>(W3, Wt, 300, 128);
  k_gemm<<<g3, 256, 0, stream>>>(Xb, Wt, dinv, T);
  k_agg<true><<<nbA, 256, 0, stream>>>(T, rp, col, dinv, b3, nullptr, Wm, sArr);

  k_gsum<<<nbN, 256, 0, stream>>>(sArr, batch, gsum, cnt);
  k_final<<<1, 512, 0, stream>>>(gsum, cnt, bm, out);
}

// Round 3
// 612.998 us; speedup vs baseline: 1.5876x; 1.2562x over previous
//
#include <hip/hip_runtime.h>
#include <hip/hip_bf16.h>

typedef __bf16 bf16;
typedef __bf16 bf16x4 __attribute__((ext_vector_type(4)));
typedef __bf16 bf16x8 __attribute__((ext_vector_type(8)));
typedef float f32x4 __attribute__((ext_vector_type(4)));

constexpr int N_NODES  = 100000;
constexpr int N_EDGES  = 800000;
constexpr int N_GRAPHS = 512;
constexpr int D_IN  = 300;
constexpr int D_HID = 300;
constexpr int D_OUT = 128;
constexpr int KP    = 320;   // padded feature stride

#define AS1(p) ((const __attribute__((address_space(1))) void*)(p))
#define AS3(p) ((__attribute__((address_space(3))) void*)(p))

// ---------------- setup kernels ----------------

__global__ __launch_bounds__(256) void k_init(int* deg, float* gsum, int* cnt) {
  int i = blockIdx.x * 256 + threadIdx.x;
  if (i < N_NODES) deg[i] = 0;
  if (i < N_GRAPHS) { gsum[i] = 0.f; cnt[i] = 0; }
}

__global__ __launch_bounds__(256) void k_deg(const int* __restrict__ ei, int* __restrict__ deg) {
  int e = blockIdx.x * 256 + threadIdx.x;
  if (e < N_EDGES) atomicAdd(&deg[ei[N_EDGES + e]], 1);
}

__global__ __launch_bounds__(256) void k_dinv(const int* __restrict__ deg, float* __restrict__ dinv) {
  int v = blockIdx.x * 256 + threadIdx.x;
  if (v < N_NODES) dinv[v] = rsqrtf((float)(deg[v] + 1));  // +1 self loop
}

__global__ __launch_bounds__(256) void k_scan1(const int* __restrict__ deg, int* __restrict__ rp,
                                               int* __restrict__ part) {
  __shared__ int sm[256];
  int tid = threadIdx.x;
  int i = blockIdx.x * 256 + tid;
  int v = (i < N_NODES) ? deg[i] : 0;
  sm[tid] = v;
  __syncthreads();
  for (int off = 1; off < 256; off <<= 1) {
    int t = (tid >= off) ? sm[tid - off] : 0;
    __syncthreads();
    sm[tid] += t;
    __syncthreads();
  }
  if (i < N_NODES) rp[i] = sm[tid] - v;
  if (tid == 255) part[blockIdx.x] = sm[255];
}

__global__ __launch_bounds__(512) void k_scan2(int* part, int nb) {
  __shared__ int sm[512];
  int tid = threadIdx.x;
  int v = (tid < nb) ? part[tid] : 0;
  sm[tid] = v;
  __syncthreads();
  for (int off = 1; off < 512; off <<= 1) {
    int t = (tid >= off) ? sm[tid - off] : 0;
    __syncthreads();
    sm[tid] += t;
    __syncthreads();
  }
  if (tid < nb) part[tid] = sm[tid] - v;
}

__global__ __launch_bounds__(256) void k_scan3(int* __restrict__ rp, const int* __restrict__ part,
                                               int* __restrict__ cur) {
  int i = blockIdx.x * 256 + threadIdx.x;
  if (i < N_NODES) {
    int r = rp[i] + part[blockIdx.x];
    rp[i] = r;
    cur[i] = r;
  }
  if (i == 0) rp[N_NODES] = N_EDGES;
}

__global__ __launch_bounds__(256) void k_fill(const int* __restrict__ ei, int* __restrict__ cur,
                                              int* __restrict__ col) {
  int e = blockIdx.x * 256 + threadIdx.x;
  if (e < N_EDGES) {
    int s = ei[e];
    int d = ei[N_EDGES + e];
    int p = atomicAdd(&cur[d], 1);
    col[p] = s;
  }
}

// ---------------- conversions ----------------

// Xs[v][k] = dinv[v] * x[v][k] as bf16, zero-padded to KP
__global__ __launch_bounds__(256) void k_conv_x(const float* __restrict__ x, const float* __restrict__ dinv,
                                                bf16* __restrict__ Xs) {
  int i = blockIdx.x * 256 + threadIdx.x;       // over N_NODES*80
  if (i >= N_NODES * (KP / 4)) return;
  int j = i % (KP / 4);
  int v = i / (KP / 4);
  float4 f = make_float4(0.f, 0.f, 0.f, 0.f);
  if (j < D_IN / 4) f = ((const float4*)(x + (size_t)v * D_IN))[j];
  float dv = dinv[v];
  bf16x4 o;
  o[0] = (bf16)(f.x * dv); o[1] = (bf16)(f.y * dv); o[2] = (bf16)(f.z * dv); o[3] = (bf16)(f.w * dv);
  *(bf16x4*)(Xs + (size_t)v * KP + j * 4) = o;
}

// Wt[n][k] = W[k][n], zero-padded to [KP][KP]
__global__ __launch_bounds__(256) void k_conv_w(const float* __restrict__ W, bf16* __restrict__ Wt,
                                                int Kin, int Nin) {
  int i = blockIdx.x * 256 + threadIdx.x;
  if (i >= KP * KP) return;
  int k = i % KP;
  int n = i / KP;
  float f = (k < Kin && n < Nin) ? W[k * Nin + n] : 0.f;
  Wt[i] = (bf16)f;
}

// ---------------- aggregation (pre-GEMM, bf16): Ab[v] = dinv[v]*(sum_nbr in[u] + in[v]) ----------------
// in rows are pre-scaled by dinv[u]. One wave per node.
// Lane l covers cols 4l..4l+3 (0..255) and, for l<11, cols 256+4l..+3 (256..299).

__global__ __launch_bounds__(256) void k_aggb(const bf16* __restrict__ in, const int* __restrict__ rp,
                                              const int* __restrict__ col, const float* __restrict__ dinv,
                                              bf16* __restrict__ out) {
  int w = threadIdx.x >> 6, l = threadIdx.x & 63;
  int v = blockIdx.x * 4 + w;
  if (v >= N_NODES) return;
  float a0[4] = {0.f, 0.f, 0.f, 0.f};
  float a1[4] = {0.f, 0.f, 0.f, 0.f};
  int s = rp[v], e = rp[v + 1];
#pragma unroll 2
  for (int i = s; i <= e; ++i) {               // neighbors, then self at i==e
    int u = (i < e) ? col[i] : v;
    const bf16* r = in + (size_t)u * KP;
    bf16x4 p = *(const bf16x4*)(r + 4 * l);
    a0[0] += (float)p[0]; a0[1] += (float)p[1]; a0[2] += (float)p[2]; a0[3] += (float)p[3];
    if (l < 11) {
      bf16x4 p2 = *(const bf16x4*)(r + 256 + 4 * l);
      a1[0] += (float)p2[0]; a1[1] += (float)p2[1]; a1[2] += (float)p2[2]; a1[3] += (float)p2[3];
    }
  }
  float dv = dinv[v];
  bf16x4 o;
  o[0] = (bf16)(a0[0] * dv); o[1] = (bf16)(a0[1] * dv);
  o[2] = (bf16)(a0[2] * dv); o[3] = (bf16)(a0[3] * dv);
  *(bf16x4*)(out + (size_t)v * KP + 4 * l) = o;
  if (l < 16) {                                // cols 256..319; l>=11 lanes write zeros (pads)
    bf16x4 o2;
    o2[0] = (bf16)(a1[0] * dv); o2[1] = (bf16)(a1[1] * dv);
    o2[2] = (bf16)(a1[2] * dv); o2[3] = (bf16)(a1[3] * dv);
    *(bf16x4*)(out + (size_t)v * KP + 256 + 4 * l) = o2;
  }
}

// ---------------- GEMM: tile 64 x NP (full N), fused epilogue ----------------
// A: [N][KP] bf16 (k-contig). Bt: [KP][KP] bf16 n-major (k-contig).
// !LAST: H[row][c] = dinv[row]*relu(acc + bias[c])  (bf16, pads auto-zero)
// LAST : sArr[row] = sum_c relu(acc + bias[c])*Wm[c]   (row-dot fused, WN must be 1)

template <int NP, int WM, int WN, bool LAST>
__global__ __launch_bounds__(256) void k_gemm(const bf16* __restrict__ A, const bf16* __restrict__ Bt,
                                              const float* __restrict__ dinv, const float* __restrict__ bias,
                                              const float* __restrict__ Wm, bf16* __restrict__ H,
                                              float* __restrict__ sArr) {
  constexpr int WROWS = 64 / WM;     // rows per wave
  constexpr int MI    = WROWS / 16;  // row fragments
  constexpr int WCOLS = NP / WN;     // cols per wave
  constexpr int NC    = WCOLS / 16;  // col fragments
  constexpr int NB    = NP / 64;     // B staging instrs per thread per k-step
  __shared__ __attribute__((aligned(16))) bf16 sA[64 * 32];
  __shared__ __attribute__((aligned(16))) bf16 sB[NP * 32];
  int m0 = blockIdx.x * 64;
  int tid = threadIdx.x;
  int w = tid >> 6, l = tid & 63;
  int wm = w / WN, wn = w % WN;

  int rA = m0 + w * 16 + (l >> 2);
  if (rA > N_NODES - 1) rA = N_NODES - 1;      // clamp; junk rows masked on store
  const bf16* gA = A + (size_t)rA * KP + (l & 3) * 8;
  bf16* lA = &sA[w * 512];

  f32x4 acc[MI][NC] = {};
  int la = l & 15, q = l >> 4, kk = q * 8;

  for (int k0 = 0; k0 < KP; k0 += 32) {
    __builtin_amdgcn_global_load_lds(AS1(gA + k0), AS3(lA), 16, 0, 0);
#pragma unroll
    for (int i = 0; i < NB; ++i) {
      int rB = i * 64 + w * 16 + (l >> 2);
      const bf16* gB = Bt + (size_t)rB * KP + k0 + (l & 3) * 8;
      __builtin_amdgcn_global_load_lds(AS1(gB), AS3(&sB[i * 2048 + w * 512]), 16, 0, 0);
    }
    __syncthreads();

    bf16x8 af[MI];
#pragma unroll
    for (int mi = 0; mi < MI; ++mi)
      af[mi] = *(const bf16x8*)&sA[(wm * WROWS + mi * 16 + la) * 32 + kk];
#pragma unroll
    for (int nc = 0; nc < NC; ++nc) {
      bf16x8 bfr = *(const bf16x8*)&sB[(wn * WCOLS + nc * 16 + la) * 32 + kk];
#pragma unroll
      for (int mi = 0; mi < MI; ++mi)
        acc[mi][nc] = __builtin_amdgcn_mfma_f32_16x16x32_bf16(af[mi], bfr, acc[mi][nc], 0, 0, 0);
    }
    __syncthreads();
  }

  // C/D layout: col = lane&15, row = (lane>>4)*4 + reg
  int rbase = m0 + wm * WROWS + q * 4;
  if (!LAST) {
    float bc[NC];
#pragma unroll
    for (int nc = 0; nc < NC; ++nc) {
      int c = wn * WCOLS + nc * 16 + la;
      bc[nc] = (c < D_HID) ? bias[c] : 0.f;    // pad cols: acc=0, bias=0 -> stores 0
    }
#pragma unroll
    for (int mi = 0; mi < MI; ++mi) {
#pragma unroll
      for (int r = 0; r < 4; ++r) {
        int row = rbase + mi * 16 + r;
        if (row < N_NODES) {
          float dv = dinv[row];
#pragma unroll
          for (int nc = 0; nc < NC; ++nc) {
            int c = wn * WCOLS + nc * 16 + la;
            H[(size_t)row * KP + c] = (bf16)(fmaxf(acc[mi][nc][r] + bc[nc], 0.f) * dv);
          }
        }
      }
    }
  } else {
    float bc[NC], wc[NC];
#pragma unroll
    for (int nc = 0; nc < NC; ++nc) {
      int c = nc * 16 + la;                    // WN==1
      bc[nc] = bias[c];
      wc[nc] = Wm[c];
    }
    float sv[4];
#pragma unroll
    for (int r = 0; r < 4; ++r) {
      sv[r] = 0.f;
#pragma unroll
      for (int nc = 0; nc < NC; ++nc)
        sv[r] += fmaxf(acc[0][nc][r] + bc[nc], 0.f) * wc[nc];
    }
#pragma unroll
    for (int m = 1; m < 16; m <<= 1) {
#pragma unroll
      for (int r = 0; r < 4; ++r) sv[r] += __shfl_xor(sv[r], m);
    }
    if (la == 0) {
#pragma unroll
      for (int r = 0; r < 4; ++r) {
        int row = rbase + r;
        if (row < N_NODES) sArr[row] = sv[r];
      }
    }
  }
}

// ---------------- pooled reduction ----------------

__global__ __launch_bounds__(256) void k_gsum(const float* __restrict__ sArr, const int* __restrict__ batch,
                                              float* __restrict__ gsum, int* __restrict__ cnt) {
  __shared__ float lsum[N_GRAPHS];
  __shared__ int   lcnt[N_GRAPHS];
  int tid = threadIdx.x;
  lsum[tid] = 0.f; lsum[tid + 256] = 0.f;
  lcnt[tid] = 0;   lcnt[tid + 256] = 0;
  __syncthreads();
  int v = blockIdx.x * 256 + tid;
  if (v < N_NODES) {
    int b = batch[v];
    atomicAdd(&lsum[b], sArr[v]);
    atomicAdd(&lcnt[b], 1);
  }
  __syncthreads();
  for (int g = tid; g < N_GRAPHS; g += 256) {
    int c = lcnt[g];
    if (c) { atomicAdd(&gsum[g], lsum[g]); atomicAdd(&cnt[g], c); }
  }
}

__global__ __launch_bounds__(512) void k_final(const float* __restrict__ gsum, const int* __restrict__ cnt,
                                               const float* __restrict__ bm, float* __restrict__ out) {
  int g = blockIdx.x * 512 + threadIdx.x;
  if (g < N_GRAPHS) out[g] = gsum[g] / fmaxf((float)cnt[g], 1.f) + bm[0];
}

// ---------------- launch ----------------

extern "C" void kernel_launch(void* const* d_in, const int* in_sizes, int n_in,
                              void* d_out, int out_size, void* d_ws, size_t ws_size,
                              hipStream_t stream) {
  const float* x    = (const float*)d_in[0];
  const int*   ei   = (const int*)d_in[1];
  const int*   batch= (const int*)d_in[2];
  const float* W1   = (const float*)d_in[3];
  const float* b1   = (const float*)d_in[4];
  const float* W2   = (const float*)d_in[5];
  const float* b2   = (const float*)d_in[6];
  const float* W3   = (const float*)d_in[7];
  const float* b3   = (const float*)d_in[8];
  const float* Wm   = (const float*)d_in[9];
  const float* bm   = (const float*)d_in[10];
  float* out = (float*)d_out;

  char* ws = (char*)d_ws;
  size_t off = 0;
  auto alloc = [&](size_t bytes) {
    void* p = ws + off;
    off = (off + bytes + 255) & ~(size_t)255;
    return p;
  };
  bf16*  Xs   = (bf16*)alloc((size_t)N_NODES * KP * sizeof(bf16));   // 64 MB; reused as H
  bf16*  Ab   = (bf16*)alloc((size_t)N_NODES * KP * sizeof(bf16));   // 64 MB
  bf16*  Wt   = (bf16*)alloc((size_t)KP * KP * sizeof(bf16));
  int*   deg  = (int*)alloc((size_t)N_NODES * 4);
  float* dinv = (float*)alloc((size_t)N_NODES * 4);
  int*   rp   = (int*)alloc((size_t)(N_NODES + 1) * 4);
  int*   cur  = (int*)alloc((size_t)N_NODES * 4);
  int*   col  = (int*)alloc((size_t)N_EDGES * 4);
  int*   part = (int*)alloc(1024 * 4);
  float* sArr = (float*)alloc((size_t)N_NODES * 4);
  float* gsum = (float*)alloc((size_t)N_GRAPHS * 4);
  int*   cnt  = (int*)alloc((size_t)N_GRAPHS * 4);
  bf16*  H    = Xs;   // Xs dead after layer-1 agg

  int nbN = (N_NODES + 255) / 256;   // 391
  int nbE = (N_EDGES + 255) / 256;   // 3125
  int nbA = (N_NODES + 3) / 4;       // 25000
  int nbG = (N_NODES + 63) / 64;     // 1563
  int nbW = (KP * KP + 255) / 256;

  k_init<<<nbN, 256, 0, stream>>>(deg, gsum, cnt);
  k_deg<<<nbE, 256, 0, stream>>>(ei, deg);
  k_dinv<<<nbN, 256, 0, stream>>>(deg, dinv);
  k_scan1<<<nbN, 256, 0, stream>>>(deg, rp, part);
  k_scan2<<<1, 512, 0, stream>>>(part, nbN);
  k_scan3<<<nbN, 256, 0, stream>>>(rp, part, cur);
  k_fill<<<nbE, 256, 0, stream>>>(ei, cur, col);
  k_conv_x<<<(N_NODES * (KP / 4) + 255) / 256, 256, 0, stream>>>(x, dinv, Xs);

  // layer 1
  k_conv_w<<<nbW, 256, 0, stream>>>(W1, Wt, 300, 300);
  k_aggb<<<nbA, 256, 0, stream>>>(Xs, rp, col, dinv, Ab);
  k_gemm<KP, 2, 2, false><<<nbG, 256, 0, stream>>>(Ab, Wt, dinv, b1, nullptr, H, nullptr);
  // layer 2
  k_conv_w<<<nbW, 256, 0, stream>>>(W2, Wt, 300, 300);
  k_aggb<<<nbA, 256, 0, stream>>>(H, rp, col, dinv, Ab);
  k_gemm<KP, 2, 2, false><<<nbG, 256, 0, stream>>>(Ab, Wt, dinv, b2, nullptr, H, nullptr);
  // layer 3
  k_conv_w<<<nbW, 256, 0, stream>>>(W3, Wt, 300, 128);
  k_aggb<<<nbA, 256, 0, stream>>>(H, rp, col, dinv, Ab);
  k_gemm<128, 4, 1, true><<<nbG, 256, 0, stream>>>(Ab, Wt, dinv, b3, Wm, nullptr, sArr);

  k_gsum<<<nbN, 256, 0, stream>>>(sArr, batch, gsum, cnt);
  k_final<<<1, 512, 0, stream>>>(gsum, cnt, bm, out);
}

// Round 4
// 518.208 us; speedup vs baseline: 1.8780x; 1.1829x over previous
//
#include <hip/hip_runtime.h>
#include <hip/hip_bf16.h>

typedef __bf16 bf16;
typedef __bf16 bf16x4 __attribute__((ext_vector_type(4)));
typedef __bf16 bf16x8 __attribute__((ext_vector_type(8)));
typedef float f32x4 __attribute__((ext_vector_type(4)));

constexpr int N_NODES  = 100000;
constexpr int N_EDGES  = 800000;
constexpr int N_GRAPHS = 512;
constexpr int D_IN  = 300;
constexpr int D_HID = 300;
constexpr int D_OUT = 128;
constexpr int KP    = 320;   // padded feature stride

#define AS1(p) ((const __attribute__((address_space(1))) void*)(p))
#define AS3(p) ((__attribute__((address_space(3))) void*)(p))

// ---------------- setup kernels ----------------

__global__ __launch_bounds__(256) void k_init(int* deg, float* gsum, int* cnt) {
  int i = blockIdx.x * 256 + threadIdx.x;
  if (i < N_NODES) deg[i] = 0;
  if (i < N_GRAPHS) { gsum[i] = 0.f; cnt[i] = 0; }
}

__global__ __launch_bounds__(256) void k_deg(const int* __restrict__ ei, int* __restrict__ deg) {
  int e = blockIdx.x * 256 + threadIdx.x;
  if (e < N_EDGES) atomicAdd(&deg[ei[N_EDGES + e]], 1);
}

__global__ __launch_bounds__(256) void k_dinv(const int* __restrict__ deg, float* __restrict__ dinv) {
  int v = blockIdx.x * 256 + threadIdx.x;
  if (v < N_NODES) dinv[v] = rsqrtf((float)(deg[v] + 1));  // +1 self loop
}

__global__ __launch_bounds__(256) void k_scan1(const int* __restrict__ deg, int* __restrict__ rp,
                                               int* __restrict__ part) {
  __shared__ int sm[256];
  int tid = threadIdx.x;
  int i = blockIdx.x * 256 + tid;
  int v = (i < N_NODES) ? deg[i] : 0;
  sm[tid] = v;
  __syncthreads();
  for (int off = 1; off < 256; off <<= 1) {
    int t = (tid >= off) ? sm[tid - off] : 0;
    __syncthreads();
    sm[tid] += t;
    __syncthreads();
  }
  if (i < N_NODES) rp[i] = sm[tid] - v;
  if (tid == 255) part[blockIdx.x] = sm[255];
}

__global__ __launch_bounds__(512) void k_scan2(int* part, int nb) {
  __shared__ int sm[512];
  int tid = threadIdx.x;
  int v = (tid < nb) ? part[tid] : 0;
  sm[tid] = v;
  __syncthreads();
  for (int off = 1; off < 512; off <<= 1) {
    int t = (tid >= off) ? sm[tid - off] : 0;
    __syncthreads();
    sm[tid] += t;
    __syncthreads();
  }
  if (tid < nb) part[tid] = sm[tid] - v;
}

__global__ __launch_bounds__(256) void k_scan3(int* __restrict__ rp, const int* __restrict__ part,
                                               int* __restrict__ cur) {
  int i = blockIdx.x * 256 + threadIdx.x;
  if (i < N_NODES) {
    int r = rp[i] + part[blockIdx.x];
    rp[i] = r;
    cur[i] = r;
  }
  if (i == 0) rp[N_NODES] = N_EDGES;
}

__global__ __launch_bounds__(256) void k_fill(const int* __restrict__ ei, int* __restrict__ cur,
                                              int* __restrict__ col) {
  int e = blockIdx.x * 256 + threadIdx.x;
  if (e < N_EDGES) {
    int s = ei[e];
    int d = ei[N_EDGES + e];
    int p = atomicAdd(&cur[d], 1);
    col[p] = s;
  }
}

// ---------------- conversions ----------------

// Xs[v][k] = dinv[v] * x[v][k] as bf16, zero-padded to KP
__global__ __launch_bounds__(256) void k_conv_x(const float* __restrict__ x, const float* __restrict__ dinv,
                                                bf16* __restrict__ Xs) {
  int i = blockIdx.x * 256 + threadIdx.x;       // over N_NODES*80
  if (i >= N_NODES * (KP / 4)) return;
  int j = i % (KP / 4);
  int v = i / (KP / 4);
  float4 f = make_float4(0.f, 0.f, 0.f, 0.f);
  if (j < D_IN / 4) f = ((const float4*)(x + (size_t)v * D_IN))[j];
  float dv = dinv[v];
  bf16x4 o;
  o[0] = (bf16)(f.x * dv); o[1] = (bf16)(f.y * dv); o[2] = (bf16)(f.z * dv); o[3] = (bf16)(f.w * dv);
  *(bf16x4*)(Xs + (size_t)v * KP + j * 4) = o;
}

// Wt[n][k] = W[k][n], zero-padded to [KP][KP]
__global__ __launch_bounds__(256) void k_conv_w(const float* __restrict__ W, bf16* __restrict__ Wt,
                                                int Kin, int Nin) {
  int i = blockIdx.x * 256 + threadIdx.x;
  if (i >= KP * KP) return;
  int k = i % KP;
  int n = i / KP;
  float f = (k < Kin && n < Nin) ? W[k * Nin + n] : 0.f;
  Wt[i] = (bf16)f;
}

// ---------------- aggregation (pre-GEMM, bf16): out[v] = dinv[v]*(sum_nbr in[u] + in[v]) ----------------
// in rows pre-scaled by dinv[u]. One wave per node; lanes 0..39 each own 8 cols (bf16x8, one
// 640B load per neighbor). Neighbor loop unrolled x4 with 2 accumulator sets -> 4 loads in flight.

__global__ __launch_bounds__(256) void k_aggb(const bf16* __restrict__ in, const int* __restrict__ rp,
                                              const int* __restrict__ col, const float* __restrict__ dinv,
                                              bf16* __restrict__ out) {
  int w = threadIdx.x >> 6, l = threadIdx.x & 63;
  int v = blockIdx.x * 4 + w;
  if (v >= N_NODES) return;
  if (l >= 40) return;                         // 40 lanes x 8 cols = 320
  const size_t co = (size_t)8 * l;

  float A0[8], A1[8];
  {                                            // init with self row
    bf16x8 p = *(const bf16x8*)(in + (size_t)v * KP + co);
#pragma unroll
    for (int j = 0; j < 8; ++j) { A0[j] = (float)p[j]; A1[j] = 0.f; }
  }
  int s = rp[v], e = rp[v + 1];
  int i = s;
  for (; i + 4 <= e; i += 4) {
    int u0 = col[i], u1 = col[i + 1], u2 = col[i + 2], u3 = col[i + 3];
    bf16x8 p0 = *(const bf16x8*)(in + (size_t)u0 * KP + co);
    bf16x8 p1 = *(const bf16x8*)(in + (size_t)u1 * KP + co);
    bf16x8 p2 = *(const bf16x8*)(in + (size_t)u2 * KP + co);
    bf16x8 p3 = *(const bf16x8*)(in + (size_t)u3 * KP + co);
#pragma unroll
    for (int j = 0; j < 8; ++j) {
      A0[j] += (float)p0[j] + (float)p2[j];
      A1[j] += (float)p1[j] + (float)p3[j];
    }
  }
  for (; i + 2 <= e; i += 2) {
    int u0 = col[i], u1 = col[i + 1];
    bf16x8 p0 = *(const bf16x8*)(in + (size_t)u0 * KP + co);
    bf16x8 p1 = *(const bf16x8*)(in + (size_t)u1 * KP + co);
#pragma unroll
    for (int j = 0; j < 8; ++j) { A0[j] += (float)p0[j]; A1[j] += (float)p1[j]; }
  }
  if (i < e) {
    int u0 = col[i];
    bf16x8 p0 = *(const bf16x8*)(in + (size_t)u0 * KP + co);
#pragma unroll
    for (int j = 0; j < 8; ++j) A0[j] += (float)p0[j];
  }
  float dv = dinv[v];
  bf16x8 o;
#pragma unroll
  for (int j = 0; j < 8; ++j) o[j] = (bf16)((A0[j] + A1[j]) * dv);
  *(bf16x8*)(out + (size_t)v * KP + co) = o;
}

// ---------------- GEMM: tile 64 x NP (full N), fused epilogue ----------------
// A: [N][KP] bf16 (k-contig). Bt: [KP][KP] bf16 n-major (k-contig).
// !LAST: H[row][c] = dinv[row]*relu(acc + bias[c])  (bf16, pads auto-zero)
// LAST : sArr[row] = sum_c relu(acc + bias[c])*Wm[c]   (row-dot fused, WN must be 1)

template <int NP, int WM, int WN, bool LAST>
__global__ __launch_bounds__(256) void k_gemm(const bf16* __restrict__ A, const bf16* __restrict__ Bt,
                                              const float* __restrict__ dinv, const float* __restrict__ bias,
                                              const float* __restrict__ Wm, bf16* __restrict__ H,
                                              float* __restrict__ sArr) {
  constexpr int WROWS = 64 / WM;
  constexpr int MI    = WROWS / 16;
  constexpr int WCOLS = NP / WN;
  constexpr int NC    = WCOLS / 16;
  constexpr int NB    = NP / 64;
  __shared__ __attribute__((aligned(16))) bf16 sA[64 * 32];
  __shared__ __attribute__((aligned(16))) bf16 sB[NP * 32];
  int m0 = blockIdx.x * 64;
  int tid = threadIdx.x;
  int w = tid >> 6, l = tid & 63;
  int wm = w / WN, wn = w % WN;

  int rA = m0 + w * 16 + (l >> 2);
  if (rA > N_NODES - 1) rA = N_NODES - 1;
  const bf16* gA = A + (size_t)rA * KP + (l & 3) * 8;
  bf16* lA = &sA[w * 512];

  f32x4 acc[MI][NC] = {};
  int la = l & 15, q = l >> 4, kk = q * 8;

  for (int k0 = 0; k0 < KP; k0 += 32) {
    __builtin_amdgcn_global_load_lds(AS1(gA + k0), AS3(lA), 16, 0, 0);
#pragma unroll
    for (int i = 0; i < NB; ++i) {
      int rB = i * 64 + w * 16 + (l >> 2);
      const bf16* gB = Bt + (size_t)rB * KP + k0 + (l & 3) * 8;
      __builtin_amdgcn_global_load_lds(AS1(gB), AS3(&sB[i * 2048 + w * 512]), 16, 0, 0);
    }
    __syncthreads();

    bf16x8 af[MI];
#pragma unroll
    for (int mi = 0; mi < MI; ++mi)
      af[mi] = *(const bf16x8*)&sA[(wm * WROWS + mi * 16 + la) * 32 + kk];
#pragma unroll
    for (int nc = 0; nc < NC; ++nc) {
      bf16x8 bfr = *(const bf16x8*)&sB[(wn * WCOLS + nc * 16 + la) * 32 + kk];
#pragma unroll
      for (int mi = 0; mi < MI; ++mi)
        acc[mi][nc] = __builtin_amdgcn_mfma_f32_16x16x32_bf16(af[mi], bfr, acc[mi][nc], 0, 0, 0);
    }
    __syncthreads();
  }

  int rbase = m0 + wm * WROWS + q * 4;
  if (!LAST) {
    float bc[NC];
#pragma unroll
    for (int nc = 0; nc < NC; ++nc) {
      int c = wn * WCOLS + nc * 16 + la;
      bc[nc] = (c < D_HID) ? bias[c] : 0.f;
    }
#pragma unroll
    for (int mi = 0; mi < MI; ++mi) {
#pragma unroll
      for (int r = 0; r < 4; ++r) {
        int row = rbase + mi * 16 + r;
        if (row < N_NODES) {
          float dv = dinv[row];
#pragma unroll
          for (int nc = 0; nc < NC; ++nc) {
            int c = wn * WCOLS + nc * 16 + la;
            H[(size_t)row * KP + c] = (bf16)(fmaxf(acc[mi][nc][r] + bc[nc], 0.f) * dv);
          }
        }
      }
    }
  } else {
    float bc[NC], wc[NC];
#pragma unroll
    for (int nc = 0; nc < NC; ++nc) {
      int c = nc * 16 + la;
      bc[nc] = bias[c];
      wc[nc] = Wm[c];
    }
    float sv[4];
#pragma unroll
    for (int r = 0; r < 4; ++r) {
      sv[r] = 0.f;
#pragma unroll
      for (int nc = 0; nc < NC; ++nc)
        sv[r] += fmaxf(acc[0][nc][r] + bc[nc], 0.f) * wc[nc];
    }
#pragma unroll
    for (int m = 1; m < 16; m <<= 1) {
#pragma unroll
      for (int r = 0; r < 4; ++r) sv[r] += __shfl_xor(sv[r], m);
    }
    if (la == 0) {
#pragma unroll
      for (int r = 0; r < 4; ++r) {
        int row = rbase + r;
        if (row < N_NODES) sArr[row] = sv[r];
      }
    }
  }
}

// ---------------- pooled reduction ----------------

__global__ __launch_bounds__(256) void k_gsum(const float* __restrict__ sArr, const int* __restrict__ batch,
                                              float* __restrict__ gsum, int* __restrict__ cnt) {
  __shared__ float lsum[N_GRAPHS];
  __shared__ int   lcnt[N_GRAPHS];
  int tid = threadIdx.x;
  lsum[tid] = 0.f; lsum[tid + 256] = 0.f;
  lcnt[tid] = 0;   lcnt[tid + 256] = 0;
  __syncthreads();
  int v = blockIdx.x * 256 + tid;
  if (v < N_NODES) {
    int b = batch[v];
    atomicAdd(&lsum[b], sArr[v]);
    atomicAdd(&lcnt[b], 1);
  }
  __syncthreads();
  for (int g = tid; g < N_GRAPHS; g += 256) {
    int c = lcnt[g];
    if (c) { atomicAdd(&gsum[g], lsum[g]); atomicAdd(&cnt[g], c); }
  }
}

__global__ __launch_bounds__(512) void k_final(const float* __restrict__ gsum, const int* __restrict__ cnt,
                                               const float* __restrict__ bm, float* __restrict__ out) {
  int g = blockIdx.x * 512 + threadIdx.x;
  if (g < N_GRAPHS) out[g] = gsum[g] / fmaxf((float)cnt[g], 1.f) + bm[0];
}

// ---------------- launch ----------------

extern "C" void kernel_launch(void* const* d_in, const int* in_sizes, int n_in,
                              void* d_out, int out_size, void* d_ws, size_t ws_size,
                              hipStream_t stream) {
  const float* x    = (const float*)d_in[0];
  const int*   ei   = (const int*)d_in[1];
  const int*   batch= (const int*)d_in[2];
  const float* W1   = (const float*)d_in[3];
  const float* b1   = (const float*)d_in[4];
  const float* W2   = (const float*)d_in[5];
  const float* b2   = (const float*)d_in[6];
  const float* W3   = (const float*)d_in[7];
  const float* b3   = (const float*)d_in[8];
  const float* Wm   = (const float*)d_in[9];
  const float* bm   = (const float*)d_in[10];
  float* out = (float*)d_out;

  char* ws = (char*)d_ws;
  size_t off = 0;
  auto alloc = [&](size_t bytes) {
    void* p = ws + off;
    off = (off + bytes + 255) & ~(size_t)255;
    return p;
  };
  bf16*  Xs   = (bf16*)alloc((size_t)N_NODES * KP * sizeof(bf16));   // 64 MB; reused as H
  bf16*  Ab   = (bf16*)alloc((size_t)N_NODES * KP * sizeof(bf16));   // 64 MB
  bf16*  Wt   = (bf16*)alloc((size_t)KP * KP * sizeof(bf16));
  int*   deg  = (int*)alloc((size_t)N_NODES * 4);
  float* dinv = (float*)alloc((size_t)N_NODES * 4);
  int*   rp   = (int*)alloc((size_t)(N_NODES + 1) * 4);
  int*   cur  = (int*)alloc((size_t)N_NODES * 4);
  int*   col  = (int*)alloc((size_t)N_EDGES * 4);
  int*   part = (int*)alloc(1024 * 4);
  float* sArr = (float*)alloc((size_t)N_NODES * 4);
  float* gsum = (float*)alloc((size_t)N_GRAPHS * 4);
  int*   cnt  = (int*)alloc((size_t)N_GRAPHS * 4);
  bf16*  H    = Xs;   // Xs dead after layer-1 agg

  int nbN = (N_NODES + 255) / 256;   // 391
  int nbE = (N_EDGES + 255) / 256;   // 3125
  int nbA = (N_NODES + 3) / 4;       // 25000
  int nbG = (N_NODES + 63) / 64;     // 1563
  int nbW = (KP * KP + 255) / 256;

  k_init<<<nbN, 256, 0, stream>>>(deg, gsum, cnt);
  k_deg<<<nbE, 256, 0, stream>>>(ei, deg);
  k_dinv<<<nbN, 256, 0, stream>>>(deg, dinv);
  k_scan1<<<nbN, 256, 0, stream>>>(deg, rp, part);
  k_scan2<<<1, 512, 0, stream>>>(part, nbN);
  k_scan3<<<nbN, 256, 0, stream>>>(rp, part, cur);
  k_fill<<<nbE, 256, 0, stream>>>(ei, cur, col);
  k_conv_x<<<(N_NODES * (KP / 4) + 255) / 256, 256, 0, stream>>>(x, dinv, Xs);

  // layer 1
  k_conv_w<<<nbW, 256, 0, stream>>>(W1, Wt, 300, 300);
  k_aggb<<<nbA, 256, 0, stream>>>(Xs, rp, col, dinv, Ab);
  k_gemm<KP, 2, 2, false><<<nbG, 256, 0, stream>>>(Ab, Wt, dinv, b1, nullptr, H, nullptr);
  // layer 2
  k_conv_w<<<nbW, 256, 0, stream>>>(W2, Wt, 300, 300);
  k_aggb<<<nbA, 256, 0, stream>>>(H, rp, col, dinv, Ab);
  k_gemm<KP, 2, 2, false><<<nbG, 256, 0, stream>>>(Ab, Wt, dinv, b2, nullptr, H, nullptr);
  // layer 3
  k_conv_w<<<nbW, 256, 0, stream>>>(W3, Wt, 300, 128);
  k_aggb<<<nbA, 256, 0, stream>>>(H, rp, col, dinv, Ab);
  k_gemm<128, 4, 1, true><<<nbG, 256, 0, stream>>>(Ab, Wt, dinv, b3, Wm, nullptr, sArr);

  k_gsum<<<nbN, 256, 0, stream>>>(sArr, batch, gsum, cnt);
  k_final<<<1, 512, 0, stream>>>(gsum, cnt, bm, out);
}

// Round 5
// 499.122 us; speedup vs baseline: 1.9498x; 1.0382x over previous
//
#include <hip/hip_runtime.h>
#include <hip/hip_bf16.h>

typedef __bf16 bf16;
typedef __bf16 bf16x4 __attribute__((ext_vector_type(4)));
typedef __bf16 bf16x8 __attribute__((ext_vector_type(8)));
typedef float f32x4 __attribute__((ext_vector_type(4)));

constexpr int N_NODES  = 100000;
constexpr int N_EDGES  = 800000;
constexpr int N_GRAPHS = 512;
constexpr int D_IN  = 300;
constexpr int D_HID = 300;
constexpr int D_OUT = 128;
constexpr int KP    = 320;   // padded feature stride
constexpr int MT    = 128;   // GEMM M-tile rows
constexpr int NTILE = (N_NODES + MT - 1) / MT;   // 782
constexpr int NPAD  = NTILE * MT;                // 100096 (A buffers padded to this)

#define AS1(p) ((const __attribute__((address_space(1))) void*)(p))
#define AS3(p) ((__attribute__((address_space(3))) void*)(p))

// ---------------- setup kernels ----------------

__global__ __launch_bounds__(256) void k_init(int* deg, float* gsum, int* cnt) {
  int i = blockIdx.x * 256 + threadIdx.x;
  if (i < N_NODES) deg[i] = 0;
  if (i < N_GRAPHS) { gsum[i] = 0.f; cnt[i] = 0; }
}

__global__ __launch_bounds__(256) void k_deg(const int* __restrict__ ei, int* __restrict__ deg) {
  int e = blockIdx.x * 256 + threadIdx.x;
  if (e < N_EDGES) atomicAdd(&deg[ei[N_EDGES + e]], 1);
}

__global__ __launch_bounds__(256) void k_dinv(const int* __restrict__ deg, float* __restrict__ dinv) {
  int v = blockIdx.x * 256 + threadIdx.x;
  if (v < N_NODES) dinv[v] = rsqrtf((float)(deg[v] + 1));  // +1 self loop
}

__global__ __launch_bounds__(256) void k_scan1(const int* __restrict__ deg, int* __restrict__ rp,
                                               int* __restrict__ part) {
  __shared__ int sm[256];
  int tid = threadIdx.x;
  int i = blockIdx.x * 256 + tid;
  int v = (i < N_NODES) ? deg[i] : 0;
  sm[tid] = v;
  __syncthreads();
  for (int off = 1; off < 256; off <<= 1) {
    int t = (tid >= off) ? sm[tid - off] : 0;
    __syncthreads();
    sm[tid] += t;
    __syncthreads();
  }
  if (i < N_NODES) rp[i] = sm[tid] - v;
  if (tid == 255) part[blockIdx.x] = sm[255];
}

__global__ __launch_bounds__(512) void k_scan2(int* part, int nb) {
  __shared__ int sm[512];
  int tid = threadIdx.x;
  int v = (tid < nb) ? part[tid] : 0;
  sm[tid] = v;
  __syncthreads();
  for (int off = 1; off < 512; off <<= 1) {
    int t = (tid >= off) ? sm[tid - off] : 0;
    __syncthreads();
    sm[tid] += t;
    __syncthreads();
  }
  if (tid < nb) part[tid] = sm[tid] - v;
}

__global__ __launch_bounds__(256) void k_scan3(int* __restrict__ rp, const int* __restrict__ part,
                                               int* __restrict__ cur) {
  int i = blockIdx.x * 256 + threadIdx.x;
  if (i < N_NODES) {
    int r = rp[i] + part[blockIdx.x];
    rp[i] = r;
    cur[i] = r;
  }
  if (i == 0) rp[N_NODES] = N_EDGES;
}

__global__ __launch_bounds__(256) void k_fill(const int* __restrict__ ei, int* __restrict__ cur,
                                              int* __restrict__ col) {
  int e = blockIdx.x * 256 + threadIdx.x;
  if (e < N_EDGES) {
    int s = ei[e];
    int d = ei[N_EDGES + e];
    int p = atomicAdd(&cur[d], 1);
    col[p] = s;
  }
}

// ---------------- conversions ----------------

// Xs[v][k] = dinv[v] * x[v][k] as bf16, zero-padded to KP
__global__ __launch_bounds__(256) void k_conv_x(const float* __restrict__ x, const float* __restrict__ dinv,
                                                bf16* __restrict__ Xs) {
  int i = blockIdx.x * 256 + threadIdx.x;       // over N_NODES*80
  if (i >= N_NODES * (KP / 4)) return;
  int j = i % (KP / 4);
  int v = i / (KP / 4);
  float4 f = make_float4(0.f, 0.f, 0.f, 0.f);
  if (j < D_IN / 4) f = ((const float4*)(x + (size_t)v * D_IN))[j];
  float dv = dinv[v];
  bf16x4 o;
  o[0] = (bf16)(f.x * dv); o[1] = (bf16)(f.y * dv); o[2] = (bf16)(f.z * dv); o[3] = (bf16)(f.w * dv);
  *(bf16x4*)(Xs + (size_t)v * KP + j * 4) = o;
}

// Wt[n][k] = W[k][n], zero-padded to [KP][KP]
__global__ __launch_bounds__(256) void k_conv_w(const float* __restrict__ W, bf16* __restrict__ Wt,
                                                int Kin, int Nin) {
  int i = blockIdx.x * 256 + threadIdx.x;
  if (i >= KP * KP) return;
  int k = i % KP;
  int n = i / KP;
  float f = (k < Kin && n < Nin) ? W[k * Nin + n] : 0.f;
  Wt[i] = (bf16)f;
}

// ---------------- aggregation (pre-GEMM, bf16): out[v] = dinv[v]*(sum_nbr in[u] + in[v]) ----------------
// in rows pre-scaled by dinv[u]. One wave per node; lanes 0..39 each own 8 cols (bf16x8).
// Neighbor loop unrolled x8 with 2 accumulator sets -> up to 8 loads in flight.

__global__ __launch_bounds__(256) void k_aggb(const bf16* __restrict__ in, const int* __restrict__ rp,
                                              const int* __restrict__ col, const float* __restrict__ dinv,
                                              bf16* __restrict__ out) {
  int w = threadIdx.x >> 6, l = threadIdx.x & 63;
  int v = blockIdx.x * 4 + w;
  if (v >= N_NODES) return;
  if (l >= 40) return;                         // 40 lanes x 8 cols = 320
  const size_t co = (size_t)8 * l;

  float A0[8], A1[8];
  {                                            // init with self row
    bf16x8 p = *(const bf16x8*)(in + (size_t)v * KP + co);
#pragma unroll
    for (int j = 0; j < 8; ++j) { A0[j] = (float)p[j]; A1[j] = 0.f; }
  }
  int s = rp[v], e = rp[v + 1];
  int i = s;
  for (; i + 8 <= e; i += 8) {
    bf16x8 p0 = *(const bf16x8*)(in + (size_t)col[i]     * KP + co);
    bf16x8 p1 = *(const bf16x8*)(in + (size_t)col[i + 1] * KP + co);
    bf16x8 p2 = *(const bf16x8*)(in + (size_t)col[i + 2] * KP + co);
    bf16x8 p3 = *(const bf16x8*)(in + (size_t)col[i + 3] * KP + co);
    bf16x8 p4 = *(const bf16x8*)(in + (size_t)col[i + 4] * KP + co);
    bf16x8 p5 = *(const bf16x8*)(in + (size_t)col[i + 5] * KP + co);
    bf16x8 p6 = *(const bf16x8*)(in + (size_t)col[i + 6] * KP + co);
    bf16x8 p7 = *(const bf16x8*)(in + (size_t)col[i + 7] * KP + co);
#pragma unroll
    for (int j = 0; j < 8; ++j) {
      A0[j] += ((float)p0[j] + (float)p2[j]) + ((float)p4[j] + (float)p6[j]);
      A1[j] += ((float)p1[j] + (float)p3[j]) + ((float)p5[j] + (float)p7[j]);
    }
  }
  for (; i + 4 <= e; i += 4) {
    bf16x8 p0 = *(const bf16x8*)(in + (size_t)col[i]     * KP + co);
    bf16x8 p1 = *(const bf16x8*)(in + (size_t)col[i + 1] * KP + co);
    bf16x8 p2 = *(const bf16x8*)(in + (size_t)col[i + 2] * KP + co);
    bf16x8 p3 = *(const bf16x8*)(in + (size_t)col[i + 3] * KP + co);
#pragma unroll
    for (int j = 0; j < 8; ++j) {
      A0[j] += (float)p0[j] + (float)p2[j];
      A1[j] += (float)p1[j] + (float)p3[j];
    }
  }
  for (; i + 2 <= e; i += 2) {
    bf16x8 p0 = *(const bf16x8*)(in + (size_t)col[i]     * KP + co);
    bf16x8 p1 = *(const bf16x8*)(in + (size_t)col[i + 1] * KP + co);
#pragma unroll
    for (int j = 0; j < 8; ++j) { A0[j] += (float)p0[j]; A1[j] += (float)p1[j]; }
  }
  if (i < e) {
    bf16x8 p0 = *(const bf16x8*)(in + (size_t)col[i] * KP + co);
#pragma unroll
    for (int j = 0; j < 8; ++j) A0[j] += (float)p0[j];
  }
  float dv = dinv[v];
  bf16x8 o;
#pragma unroll
  for (int j = 0; j < 8; ++j) o[j] = (bf16)((A0[j] + A1[j]) * dv);
  *(bf16x8*)(out + (size_t)v * KP + co) = o;
}

// ---------------- GEMM: M-tile 128 x NP (full N), K split in 5x64, 8 waves ----------------
// A: [NPAD][KP] bf16 k-contig. Bt: [KP][KP] bf16 n-major k-contig.
// LDS rows are 128B k-chunks, XOR-swizzled (c ^ ((row&7)<<4)) via pre-swizzled GLOBAL source
// (gload_lds dest must stay linear), un-swizzled on ds_read. 2 barriers per K-chunk.
// !LAST: H[row][c] = dinv[row]*relu(acc + bias[c]);  LAST: sArr[row] = sum_c relu(acc+b)*Wm[c]

template <int NP, int WM, int WN, bool LAST>
__global__ __launch_bounds__(512, 4) void k_gemm(const bf16* __restrict__ A, const bf16* __restrict__ Bt,
                                                 const float* __restrict__ dinv, const float* __restrict__ bias,
                                                 const float* __restrict__ Wm, bf16* __restrict__ H,
                                                 float* __restrict__ sArr) {
  constexpr int WROWS = MT / WM;     // rows per wave
  constexpr int MI    = WROWS / 16;
  constexpr int WCOLS = NP / WN;     // cols per wave
  constexpr int NC    = WCOLS / 16;
  constexpr int NB_B  = NP / 64;     // B staging instrs (8192 B each)
  __shared__ __attribute__((aligned(16))) char sA[MT * 128];   // 16 KB
  __shared__ __attribute__((aligned(16))) char sB[NP * 128];   // 40/16 KB

  const int tid = threadIdx.x;
  const int w = tid >> 6, l = tid & 63;
  const int wm = w / WN, wn = w % WN;
  const int m0 = blockIdx.x * MT;

  // staging: instr i covers LDS bytes [i*8192 + tid*16, +16): row = i*64 + (tid>>3), chunk (tid&7)*16
  const int sr  = tid >> 3;                      // 0..63
  const int ssw = ((tid & 7) << 4) ^ ((sr & 7) << 4);  // swizzled byte offset within 128B row-part
  const char* Ab = (const char*)A;
  const char* Bb = (const char*)Bt;

  const int la = l & 15, q = l >> 4;
  const int msk = (la & 7) << 4;                 // read-side swizzle (row&7 == la&7 here)

  f32x4 acc[MI][NC] = {};

  for (int kh = 0; kh < 5; ++kh) {
#pragma unroll
    for (int i = 0; i < 2; ++i) {
      const char* src = Ab + (size_t)(m0 + i * 64 + sr) * 640 + kh * 128 + ssw;
      __builtin_amdgcn_global_load_lds(AS1(src), AS3(sA + i * 8192 + w * 1024), 16, 0, 0);
    }
#pragma unroll
    for (int i = 0; i < NB_B; ++i) {
      const char* src = Bb + (size_t)(i * 64 + sr) * 640 + kh * 128 + ssw;
      __builtin_amdgcn_global_load_lds(AS1(src), AS3(sB + i * 8192 + w * 1024), 16, 0, 0);
    }
    __syncthreads();                             // drains vmcnt before reads

#pragma unroll
    for (int ks = 0; ks < 2; ++ks) {
      const int cb = (ks * 64 + q * 16) ^ msk;   // swizzled byte offset of this 16B fragment
      bf16x8 af[MI];
#pragma unroll
      for (int mi = 0; mi < MI; ++mi) {
        int r = wm * WROWS + mi * 16 + la;
        af[mi] = *(const bf16x8*)(sA + r * 128 + cb);
      }
#pragma unroll
      for (int nc = 0; nc < NC; ++nc) {
        int rb = wn * WCOLS + nc * 16 + la;
        bf16x8 bfr = *(const bf16x8*)(sB + rb * 128 + cb);
#pragma unroll
        for (int mi = 0; mi < MI; ++mi)
          acc[mi][nc] = __builtin_amdgcn_mfma_f32_16x16x32_bf16(af[mi], bfr, acc[mi][nc], 0, 0, 0);
      }
    }
    __syncthreads();                             // all reads done before next stage
  }

  // C/D layout: col = lane&15, row = (lane>>4)*4 + reg
  const int rbase = m0 + wm * WROWS + q * 4;
  if (!LAST) {
    float bc[NC];
#pragma unroll
    for (int nc = 0; nc < NC; ++nc) {
      int c = wn * WCOLS + nc * 16 + la;
      bc[nc] = (c < D_HID) ? bias[c] : 0.f;      // pad cols: acc=0, bias=0 -> stores 0
    }
#pragma unroll
    for (int mi = 0; mi < MI; ++mi) {
#pragma unroll
      for (int r = 0; r < 4; ++r) {
        int row = rbase + mi * 16 + r;
        if (row < N_NODES) {
          float dv = dinv[row];
#pragma unroll
          for (int nc = 0; nc < NC; ++nc) {
            int c = wn * WCOLS + nc * 16 + la;
            H[(size_t)row * KP + c] = (bf16)(fmaxf(acc[mi][nc][r] + bc[nc], 0.f) * dv);
          }
        }
      }
    }
  } else {
    float bc[NC], wc[NC];
#pragma unroll
    for (int nc = 0; nc < NC; ++nc) {
      int c = nc * 16 + la;                      // WN==1
      bc[nc] = bias[c];
      wc[nc] = Wm[c];
    }
    float sv[4];
#pragma unroll
    for (int r = 0; r < 4; ++r) {
      sv[r] = 0.f;
#pragma unroll
      for (int nc = 0; nc < NC; ++nc)
        sv[r] += fmaxf(acc[0][nc][r] + bc[nc], 0.f) * wc[nc];
    }
#pragma unroll
    for (int m = 1; m < 16; m <<= 1) {
#pragma unroll
      for (int r = 0; r < 4; ++r) sv[r] += __shfl_xor(sv[r], m);
    }
    if (la == 0) {
#pragma unroll
      for (int r = 0; r < 4; ++r) {
        int row = rbase + r;
        if (row < N_NODES) sArr[row] = sv[r];
      }
    }
  }
}

// ---------------- pooled reduction ----------------

__global__ __launch_bounds__(256) void k_gsum(const float* __restrict__ sArr, const int* __restrict__ batch,
                                              float* __restrict__ gsum, int* __restrict__ cnt) {
  __shared__ float lsum[N_GRAPHS];
  __shared__ int   lcnt[N_GRAPHS];
  int tid = threadIdx.x;
  lsum[tid] = 0.f; lsum[tid + 256] = 0.f;
  lcnt[tid] = 0;   lcnt[tid + 256] = 0;
  __syncthreads();
  int v = blockIdx.x * 256 + tid;
  if (v < N_NODES) {
    int b = batch[v];
    atomicAdd(&lsum[b], sArr[v]);
    atomicAdd(&lcnt[b], 1);
  }
  __syncthreads();
  for (int g = tid; g < N_GRAPHS; g += 256) {
    int c = lcnt[g];
    if (c) { atomicAdd(&gsum[g], lsum[g]); atomicAdd(&cnt[g], c); }
  }
}

__global__ __launch_bounds__(512) void k_final(const float* __restrict__ gsum, const int* __restrict__ cnt,
                                               const float* __restrict__ bm, float* __restrict__ out) {
  int g = blockIdx.x * 512 + threadIdx.x;
  if (g < N_GRAPHS) out[g] = gsum[g] / fmaxf((float)cnt[g], 1.f) + bm[0];
}

// ---------------- launch ----------------

extern "C" void kernel_launch(void* const* d_in, const int* in_sizes, int n_in,
                              void* d_out, int out_size, void* d_ws, size_t ws_size,
                              hipStream_t stream) {
  const float* x    = (const float*)d_in[0];
  const int*   ei   = (const int*)d_in[1];
  const int*   batch= (const int*)d_in[2];
  const float* W1   = (const float*)d_in[3];
  const float* b1   = (const float*)d_in[4];
  const float* W2   = (const float*)d_in[5];
  const float* b2   = (const float*)d_in[6];
  const float* W3   = (const float*)d_in[7];
  const float* b3   = (const float*)d_in[8];
  const float* Wm   = (const float*)d_in[9];
  const float* bm   = (const float*)d_in[10];
  float* out = (float*)d_out;

  char* ws = (char*)d_ws;
  size_t off = 0;
  auto alloc = [&](size_t bytes) {
    void* p = ws + off;
    off = (off + bytes + 255) & ~(size_t)255;
    return p;
  };
  bf16*  Xs   = (bf16*)alloc((size_t)NPAD * KP * sizeof(bf16));    // 64 MB; reused as H
  bf16*  Ab   = (bf16*)alloc((size_t)NPAD * KP * sizeof(bf16));    // 64 MB
  bf16*  Wt   = (bf16*)alloc((size_t)KP * KP * sizeof(bf16));
  int*   deg  = (int*)alloc((size_t)N_NODES * 4);
  float* dinv = (float*)alloc((size_t)N_NODES * 4);
  int*   rp   = (int*)alloc((size_t)(N_NODES + 1) * 4);
  int*   cur  = (int*)alloc((size_t)N_NODES * 4);
  int*   col  = (int*)alloc((size_t)N_EDGES * 4);
  int*   part = (int*)alloc(1024 * 4);
  float* sArr = (float*)alloc((size_t)N_NODES * 4);
  float* gsum = (float*)alloc((size_t)N_GRAPHS * 4);
  int*   cnt  = (int*)alloc((size_t)N_GRAPHS * 4);
  bf16*  H    = Xs;   // Xs dead after layer-1 agg

  int nbN = (N_NODES + 255) / 256;   // 391
  int nbE = (N_EDGES + 255) / 256;   // 3125
  int nbA = (N_NODES + 3) / 4;       // 25000
  int nbW = (KP * KP + 255) / 256;

  k_init<<<nbN, 256, 0, stream>>>(deg, gsum, cnt);
  k_deg<<<nbE, 256, 0, stream>>>(ei, deg);
  k_dinv<<<nbN, 256, 0, stream>>>(deg, dinv);
  k_scan1<<<nbN, 256, 0, stream>>>(deg, rp, part);
  k_scan2<<<1, 512, 0, stream>>>(part, nbN);
  k_scan3<<<nbN, 256, 0, stream>>>(rp, part, cur);
  k_fill<<<nbE, 256, 0, stream>>>(ei, cur, col);
  k_conv_x<<<(N_NODES * (KP / 4) + 255) / 256, 256, 0, stream>>>(x, dinv, Xs);

  // layer 1
  k_conv_w<<<nbW, 256, 0, stream>>>(W1, Wt, 300, 300);
  k_aggb<<<nbA, 256, 0, stream>>>(Xs, rp, col, dinv, Ab);
  k_gemm<KP, 2, 4, false><<<NTILE, 512, 0, stream>>>(Ab, Wt, dinv, b1, nullptr, H, nullptr);
  // layer 2
  k_conv_w<<<nbW, 256, 0, stream>>>(W2, Wt, 300, 300);
  k_aggb<<<nbA, 256, 0, stream>>>(H, rp, col, dinv, Ab);
  k_gemm<KP, 2, 4, false><<<NTILE, 512, 0, stream>>>(Ab, Wt, dinv, b2, nullptr, H, nullptr);
  // layer 3
  k_conv_w<<<nbW, 256, 0, stream>>>(W3, Wt, 300, 128);
  k_aggb<<<nbA, 256, 0, stream>>>(H, rp, col, dinv, Ab);
  k_gemm<128, 8, 1, true><<<NTILE, 512, 0, stream>>>(Ab, Wt, dinv, b3, Wm, nullptr, sArr);

  k_gsum<<<nbN, 256, 0, stream>>>(sArr, batch, gsum, cnt);
  k_final<<<1, 512, 0, stream>>>(gsum, cnt, bm, out);
}

// Round 7
// 443.572 us; speedup vs baseline: 2.1939x; 1.1252x over previous
//
#include <hip/hip_runtime.h>
#include <hip/hip_bf16.h>

typedef __bf16 bf16;
typedef __bf16 bf16x4 __attribute__((ext_vector_type(4)));
typedef __bf16 bf16x8 __attribute__((ext_vector_type(8)));
typedef float f32x4 __attribute__((ext_vector_type(4)));

constexpr int N_NODES  = 100000;
constexpr int N_EDGES  = 800000;
constexpr int N_GRAPHS = 512;
constexpr int D_IN  = 300;
constexpr int D_HID = 300;
constexpr int D_OUT = 128;
constexpr int KP    = 320;   // padded feature stride
constexpr int MT    = 128;   // GEMM M-tile rows
constexpr int NTILE = (N_NODES + MT - 1) / MT;   // 782
constexpr int NPAD  = NTILE * MT;                // 100096

#define AS1(p) ((const __attribute__((address_space(1))) void*)(p))
#define AS3(p) ((__attribute__((address_space(3))) void*)(p))

// ---------------- setup kernels ----------------

__global__ __launch_bounds__(256) void k_init(int* deg, float* gsum, int* cnt) {
  int i = blockIdx.x * 256 + threadIdx.x;
  if (i < N_NODES) deg[i] = 0;
  if (i < N_GRAPHS) { gsum[i] = 0.f; cnt[i] = 0; }
}

__global__ __launch_bounds__(256) void k_deg(const int* __restrict__ ei, int* __restrict__ deg) {
  int e = blockIdx.x * 256 + threadIdx.x;
  if (e < N_EDGES) atomicAdd(&deg[ei[N_EDGES + e]], 1);
}

__global__ __launch_bounds__(256) void k_dinv(const int* __restrict__ deg, float* __restrict__ dinv) {
  int v = blockIdx.x * 256 + threadIdx.x;
  if (v < N_NODES) dinv[v] = rsqrtf((float)(deg[v] + 1));  // +1 self loop
}

__global__ __launch_bounds__(256) void k_scan1(const int* __restrict__ deg, int* __restrict__ rp,
                                               int* __restrict__ part) {
  __shared__ int sm[256];
  int tid = threadIdx.x;
  int i = blockIdx.x * 256 + tid;
  int v = (i < N_NODES) ? deg[i] : 0;
  sm[tid] = v;
  __syncthreads();
  for (int off = 1; off < 256; off <<= 1) {
    int t = (tid >= off) ? sm[tid - off] : 0;
    __syncthreads();
    sm[tid] += t;
    __syncthreads();
  }
  if (i < N_NODES) rp[i] = sm[tid] - v;
  if (tid == 255) part[blockIdx.x] = sm[255];
}

__global__ __launch_bounds__(512) void k_scan2(int* part, int nb) {
  __shared__ int sm[512];
  int tid = threadIdx.x;
  int v = (tid < nb) ? part[tid] : 0;
  sm[tid] = v;
  __syncthreads();
  for (int off = 1; off < 512; off <<= 1) {
    int t = (tid >= off) ? sm[tid - off] : 0;
    __syncthreads();
    sm[tid] += t;
    __syncthreads();
  }
  if (tid < nb) part[tid] = sm[tid] - v;
}

__global__ __launch_bounds__(256) void k_scan3(int* __restrict__ rp, const int* __restrict__ part,
                                               int* __restrict__ cur) {
  int i = blockIdx.x * 256 + threadIdx.x;
  if (i < N_NODES) {
    int r = rp[i] + part[blockIdx.x];
    rp[i] = r;
    cur[i] = r;
  }
  if (i == 0) rp[N_NODES] = N_EDGES;
}

__global__ __launch_bounds__(256) void k_fill(const int* __restrict__ ei, int* __restrict__ cur,
                                              int* __restrict__ col) {
  int e = blockIdx.x * 256 + threadIdx.x;
  if (e < N_EDGES) {
    int s = ei[e];
    int d = ei[N_EDGES + e];
    int p = atomicAdd(&cur[d], 1);
    col[p] = s;
  }
}

// ---------------- conversions ----------------

// Xs[v][k] = dinv[v] * x[v][k] as bf16, zero-padded to KP
__global__ __launch_bounds__(256) void k_conv_x(const float* __restrict__ x, const float* __restrict__ dinv,
                                                bf16* __restrict__ Xs) {
  int i = blockIdx.x * 256 + threadIdx.x;       // over N_NODES*80
  if (i >= N_NODES * (KP / 4)) return;
  int j = i % (KP / 4);
  int v = i / (KP / 4);
  float4 f = make_float4(0.f, 0.f, 0.f, 0.f);
  if (j < D_IN / 4) f = ((const float4*)(x + (size_t)v * D_IN))[j];
  float dv = dinv[v];
  bf16x4 o;
  o[0] = (bf16)(f.x * dv); o[1] = (bf16)(f.y * dv); o[2] = (bf16)(f.z * dv); o[3] = (bf16)(f.w * dv);
  *(bf16x4*)(Xs + (size_t)v * KP + j * 4) = o;
}

// Wt[n][k] = W[k][n], zero-padded to [KP][KP]
__global__ __launch_bounds__(256) void k_conv_w(const float* __restrict__ W, bf16* __restrict__ Wt,
                                                int Kin, int Nin) {
  int i = blockIdx.x * 256 + threadIdx.x;
  if (i >= KP * KP) return;
  int k = i % KP;
  int n = i / KP;
  float f = (k < Kin && n < Nin) ? W[k * Nin + n] : 0.f;
  Wt[i] = (bf16)f;
}

// ---------------- aggregation (pre-GEMM, bf16): out[v] = dinv[v]*(sum_nbr in[u] + in[v]) ----------------
// R4 form (VGPR 32, occ ~73%): lanes 0..39 own 8 cols; x4 unroll, 2 acc sets.

__global__ __launch_bounds__(256) void k_aggb(const bf16* __restrict__ in, const int* __restrict__ rp,
                                              const int* __restrict__ col, const float* __restrict__ dinv,
                                              bf16* __restrict__ out) {
  int w = threadIdx.x >> 6, l = threadIdx.x & 63;
  int v = blockIdx.x * 4 + w;
  if (v >= N_NODES) return;
  if (l >= 40) return;                         // 40 lanes x 8 cols = 320
  const size_t co = (size_t)8 * l;

  float A0[8], A1[8];
  {                                            // init with self row
    bf16x8 p = *(const bf16x8*)(in + (size_t)v * KP + co);
#pragma unroll
    for (int j = 0; j < 8; ++j) { A0[j] = (float)p[j]; A1[j] = 0.f; }
  }
  int s = rp[v], e = rp[v + 1];
  int i = s;
  for (; i + 4 <= e; i += 4) {
    int u0 = col[i], u1 = col[i + 1], u2 = col[i + 2], u3 = col[i + 3];
    bf16x8 p0 = *(const bf16x8*)(in + (size_t)u0 * KP + co);
    bf16x8 p1 = *(const bf16x8*)(in + (size_t)u1 * KP + co);
    bf16x8 p2 = *(const bf16x8*)(in + (size_t)u2 * KP + co);
    bf16x8 p3 = *(const bf16x8*)(in + (size_t)u3 * KP + co);
#pragma unroll
    for (int j = 0; j < 8; ++j) {
      A0[j] += (float)p0[j] + (float)p2[j];
      A1[j] += (float)p1[j] + (float)p3[j];
    }
  }
  for (; i + 2 <= e; i += 2) {
    int u0 = col[i], u1 = col[i + 1];
    bf16x8 p0 = *(const bf16x8*)(in + (size_t)u0 * KP + co);
    bf16x8 p1 = *(const bf16x8*)(in + (size_t)u1 * KP + co);
#pragma unroll
    for (int j = 0; j < 8; ++j) { A0[j] += (float)p0[j]; A1[j] += (float)p1[j]; }
  }
  if (i < e) {
    int u0 = col[i];
    bf16x8 p0 = *(const bf16x8*)(in + (size_t)u0 * KP + co);
#pragma unroll
    for (int j = 0; j < 8; ++j) A0[j] += (float)p0[j];
  }
  float dv = dinv[v];
  bf16x8 o;
#pragma unroll
  for (int j = 0; j < 8; ++j) o[j] = (bf16)((A0[j] + A1[j]) * dv);
  *(bf16x8*)(out + (size_t)v * KP + co) = o;
}

// ---------------- layer-3 post-GEMM aggregation ----------------
// T3: [NPAD][128] bf16. T3[u] = (H·W3)[u] = dinv[u]*(h2·W3)[u] — already gather-prescaled
// because H rows carry the dinv factor. 16 nodes/block, 16 lanes/node (8 cols each).
// sArr[v] = sum_d relu(dinv[v]*(sum_nbr T3[u] + T3[v])[d] + b3[d]) * Wm[d]

__global__ __launch_bounds__(256) void k_agg3(const bf16* __restrict__ T3, const int* __restrict__ rp,
                                              const int* __restrict__ col, const float* __restrict__ dinv,
                                              const float* __restrict__ bias, const float* __restrict__ Wm,
                                              float* __restrict__ sArr) {
  const int tid = threadIdx.x;
  const int c = tid & 15;                      // 16B chunk within row
  const int v = blockIdx.x * 16 + (tid >> 4);  // grid is exactly N_NODES/16
  const size_t co = (size_t)8 * c;

  float A0[8], A1[8];
  {                                            // self row
    bf16x8 p = *(const bf16x8*)(T3 + (size_t)v * 128 + co);
#pragma unroll
    for (int j = 0; j < 8; ++j) { A0[j] = (float)p[j]; A1[j] = 0.f; }
  }
  int s = rp[v], e = rp[v + 1];
  int i = s;
  for (; i + 4 <= e; i += 4) {
    int u0 = col[i], u1 = col[i + 1], u2 = col[i + 2], u3 = col[i + 3];
    bf16x8 p0 = *(const bf16x8*)(T3 + (size_t)u0 * 128 + co);
    bf16x8 p1 = *(const bf16x8*)(T3 + (size_t)u1 * 128 + co);
    bf16x8 p2 = *(const bf16x8*)(T3 + (size_t)u2 * 128 + co);
    bf16x8 p3 = *(const bf16x8*)(T3 + (size_t)u3 * 128 + co);
#pragma unroll
    for (int j = 0; j < 8; ++j) {
      A0[j] += (float)p0[j] + (float)p2[j];
      A1[j] += (float)p1[j] + (float)p3[j];
    }
  }
  for (; i + 2 <= e; i += 2) {
    int u0 = col[i], u1 = col[i + 1];
    bf16x8 p0 = *(const bf16x8*)(T3 + (size_t)u0 * 128 + co);
    bf16x8 p1 = *(const bf16x8*)(T3 + (size_t)u1 * 128 + co);
#pragma unroll
    for (int j = 0; j < 8; ++j) { A0[j] += (float)p0[j]; A1[j] += (float)p1[j]; }
  }
  if (i < e) {
    bf16x8 p0 = *(const bf16x8*)(T3 + (size_t)col[i] * 128 + co);
#pragma unroll
    for (int j = 0; j < 8; ++j) A0[j] += (float)p0[j];
  }

  float dv = dinv[v];
  float sv = 0.f;
#pragma unroll
  for (int j = 0; j < 8; ++j) {
    int d = (int)co + j;
    float val = fmaxf((A0[j] + A1[j]) * dv + bias[d], 0.f);
    sv += val * Wm[d];
  }
#pragma unroll
  for (int m = 1; m < 16; m <<= 1) sv += __shfl_xor(sv, m);  // reduce within 16-lane group
  if (c == 0) sArr[v] = sv;
}

// ---------------- GEMM: M-tile 128 x NP (full N), K split in 5x64, 8 waves ----------------
// A: [NPAD][KP] bf16 k-contig. Bt: [KP][KP] bf16 n-major k-contig.
// LDS rows are 128B k-chunks, XOR-swizzled via pre-swizzled GLOBAL source; un-swizzled on ds_read.
// EPI 0: H[row][c] = dinv[row]*relu(acc + bias[c])   (bf16, stride KP)
// EPI 1: T3[row][c] = acc                            (bf16, stride NP; input rows carry dinv already)

template <int NP, int WM, int WN, int EPI>
__global__ __launch_bounds__(512, 4) void k_gemm(const bf16* __restrict__ A, const bf16* __restrict__ Bt,
                                                 const float* __restrict__ dinv, const float* __restrict__ bias,
                                                 bf16* __restrict__ H) {
  constexpr int WROWS = MT / WM;
  constexpr int MI    = WROWS / 16;
  constexpr int WCOLS = NP / WN;
  constexpr int NC    = WCOLS / 16;
  constexpr int NB_B  = NP / 64;
  __shared__ __attribute__((aligned(16))) char sA[MT * 128];   // 16 KB
  __shared__ __attribute__((aligned(16))) char sB[NP * 128];   // 40/16 KB

  const int tid = threadIdx.x;
  const int w = tid >> 6, l = tid & 63;
  const int wm = w / WN, wn = w % WN;
  const int m0 = blockIdx.x * MT;

  const int sr  = tid >> 3;                      // staging row 0..63 per 64-row group
  const int ssw = ((tid & 7) << 4) ^ ((sr & 7) << 4);
  const char* Ab = (const char*)A;
  const char* Bb = (const char*)Bt;

  const int la = l & 15, q = l >> 4;
  const int msk = (la & 7) << 4;                 // read-side swizzle

  f32x4 acc[MI][NC] = {};

  for (int kh = 0; kh < 5; ++kh) {
#pragma unroll
    for (int i = 0; i < 2; ++i) {
      const char* src = Ab + (size_t)(m0 + i * 64 + sr) * 640 + kh * 128 + ssw;
      __builtin_amdgcn_global_load_lds(AS1(src), AS3(sA + i * 8192 + w * 1024), 16, 0, 0);
    }
#pragma unroll
    for (int i = 0; i < NB_B; ++i) {
      const char* src = Bb + (size_t)(i * 64 + sr) * 640 + kh * 128 + ssw;
      __builtin_amdgcn_global_load_lds(AS1(src), AS3(sB + i * 8192 + w * 1024), 16, 0, 0);
    }
    __syncthreads();

#pragma unroll
    for (int ks = 0; ks < 2; ++ks) {
      const int cb = (ks * 64 + q * 16) ^ msk;
      bf16x8 af[MI];
#pragma unroll
      for (int mi = 0; mi < MI; ++mi) {
        int r = wm * WROWS + mi * 16 + la;
        af[mi] = *(const bf16x8*)(sA + r * 128 + cb);
      }
#pragma unroll
      for (int nc = 0; nc < NC; ++nc) {
        int rb = wn * WCOLS + nc * 16 + la;
        bf16x8 bfr = *(const bf16x8*)(sB + rb * 128 + cb);
#pragma unroll
        for (int mi = 0; mi < MI; ++mi)
          acc[mi][nc] = __builtin_amdgcn_mfma_f32_16x16x32_bf16(af[mi], bfr, acc[mi][nc], 0, 0, 0);
      }
    }
    __syncthreads();
  }

  // C/D layout: col = lane&15, row = (lane>>4)*4 + reg
  const int rbase = m0 + wm * WROWS + q * 4;
  if (EPI == 0) {
    float bc[NC];
#pragma unroll
    for (int nc = 0; nc < NC; ++nc) {
      int c = wn * WCOLS + nc * 16 + la;
      bc[nc] = (c < D_HID) ? bias[c] : 0.f;      // pad cols: acc=0, bias=0 -> stores 0
    }
#pragma unroll
    for (int mi = 0; mi < MI; ++mi) {
#pragma unroll
      for (int r = 0; r < 4; ++r) {
        int row = rbase + mi * 16 + r;
        if (row < N_NODES) {
          float dv = dinv[row];
#pragma unroll
          for (int nc = 0; nc < NC; ++nc) {
            int c = wn * WCOLS + nc * 16 + la;
            H[(size_t)row * KP + c] = (bf16)(fmaxf(acc[mi][nc][r] + bc[nc], 0.f) * dv);
          }
        }
      }
    }
  } else {
#pragma unroll
    for (int mi = 0; mi < MI; ++mi) {
#pragma unroll
      for (int r = 0; r < 4; ++r) {
        int row = rbase + mi * 16 + r;
        if (row < N_NODES) {
#pragma unroll
          for (int nc = 0; nc < NC; ++nc) {
            int c = wn * WCOLS + nc * 16 + la;
            H[(size_t)row * NP + c] = (bf16)acc[mi][nc][r];   // NO dinv: input rows already scaled
          }
        }
      }
    }
  }
}

// ---------------- pooled reduction ----------------

__global__ __launch_bounds__(256) void k_gsum(const float* __restrict__ sArr, const int* __restrict__ batch,
                                              float* __restrict__ gsum, int* __restrict__ cnt) {
  __shared__ float lsum[N_GRAPHS];
  __shared__ int   lcnt[N_GRAPHS];
  int tid = threadIdx.x;
  lsum[tid] = 0.f; lsum[tid + 256] = 0.f;
  lcnt[tid] = 0;   lcnt[tid + 256] = 0;
  __syncthreads();
  int v = blockIdx.x * 256 + tid;
  if (v < N_NODES) {
    int b = batch[v];
    atomicAdd(&lsum[b], sArr[v]);
    atomicAdd(&lcnt[b], 1);
  }
  __syncthreads();
  for (int g = tid; g < N_GRAPHS; g += 256) {
    int c = lcnt[g];
    if (c) { atomicAdd(&gsum[g], lsum[g]); atomicAdd(&cnt[g], c); }
  }
}

__global__ __launch_bounds__(512) void k_final(const float* __restrict__ gsum, const int* __restrict__ cnt,
                                               const float* __restrict__ bm, float* __restrict__ out) {
  int g = blockIdx.x * 512 + threadIdx.x;
  if (g < N_GRAPHS) out[g] = gsum[g] / fmaxf((float)cnt[g], 1.f) + bm[0];
}

// ---------------- launch ----------------

extern "C" void kernel_launch(void* const* d_in, const int* in_sizes, int n_in,
                              void* d_out, int out_size, void* d_ws, size_t ws_size,
                              hipStream_t stream) {
  const float* x    = (const float*)d_in[0];
  const int*   ei   = (const int*)d_in[1];
  const int*   batch= (const int*)d_in[2];
  const float* W1   = (const float*)d_in[3];
  const float* b1   = (const float*)d_in[4];
  const float* W2   = (const float*)d_in[5];
  const float* b2   = (const float*)d_in[6];
  const float* W3   = (const float*)d_in[7];
  const float* b3   = (const float*)d_in[8];
  const float* Wm   = (const float*)d_in[9];
  const float* bm   = (const float*)d_in[10];
  float* out = (float*)d_out;

  char* ws = (char*)d_ws;
  size_t off = 0;
  auto alloc = [&](size_t bytes) {
    void* p = ws + off;
    off = (off + bytes + 255) & ~(size_t)255;
    return p;
  };
  bf16*  Xs   = (bf16*)alloc((size_t)NPAD * KP * sizeof(bf16));    // 64 MB; reused as H
  bf16*  Ab   = (bf16*)alloc((size_t)NPAD * KP * sizeof(bf16));    // 64 MB
  bf16*  T3   = (bf16*)alloc((size_t)NPAD * 128 * sizeof(bf16));   // 25.6 MB
  bf16*  Wt   = (bf16*)alloc((size_t)KP * KP * sizeof(bf16));
  int*   deg  = (int*)alloc((size_t)N_NODES * 4);
  float* dinv = (float*)alloc((size_t)N_NODES * 4);
  int*   rp   = (int*)alloc((size_t)(N_NODES + 1) * 4);
  int*   cur  = (int*)alloc((size_t)N_NODES * 4);
  int*   col  = (int*)alloc((size_t)N_EDGES * 4);
  int*   part = (int*)alloc(1024 * 4);
  float* sArr = (float*)alloc((size_t)N_NODES * 4);
  float* gsum = (float*)alloc((size_t)N_GRAPHS * 4);
  int*   cnt  = (int*)alloc((size_t)N_GRAPHS * 4);
  bf16*  H    = Xs;   // Xs dead after layer-1 agg

  int nbN = (N_NODES + 255) / 256;   // 391
  int nbE = (N_EDGES + 255) / 256;   // 3125
  int nbA = (N_NODES + 3) / 4;       // 25000
  int nbW = (KP * KP + 255) / 256;

  k_init<<<nbN, 256, 0, stream>>>(deg, gsum, cnt);
  k_deg<<<nbE, 256, 0, stream>>>(ei, deg);
  k_dinv<<<nbN, 256, 0, stream>>>(deg, dinv);
  k_scan1<<<nbN, 256, 0, stream>>>(deg, rp, part);
  k_scan2<<<1, 512, 0, stream>>>(part, nbN);
  k_scan3<<<nbN, 256, 0, stream>>>(rp, part, cur);
  k_fill<<<nbE, 256, 0, stream>>>(ei, cur, col);
  k_conv_x<<<(N_NODES * (KP / 4) + 255) / 256, 256, 0, stream>>>(x, dinv, Xs);

  // layer 1: aggregate (bf16) -> GEMM (bias+relu+dinv)
  k_conv_w<<<nbW, 256, 0, stream>>>(W1, Wt, 300, 300);
  k_aggb<<<nbA, 256, 0, stream>>>(Xs, rp, col, dinv, Ab);
  k_gemm<KP, 2, 4, 0><<<NTILE, 512, 0, stream>>>(Ab, Wt, dinv, b1, H);
  // layer 2
  k_conv_w<<<nbW, 256, 0, stream>>>(W2, Wt, 300, 300);
  k_aggb<<<nbA, 256, 0, stream>>>(H, rp, col, dinv, Ab);
  k_gemm<KP, 2, 4, 0><<<NTILE, 512, 0, stream>>>(Ab, Wt, dinv, b2, H);
  // layer 3: GEMM first (128-wide; H rows already dinv-scaled), then aggregate + bias + relu + Wm-dot
  k_conv_w<<<nbW, 256, 0, stream>>>(W3, Wt, 300, 128);
  k_gemm<128, 8, 1, 1><<<NTILE, 512, 0, stream>>>(H, Wt, dinv, nullptr, T3);
  k_agg3<<<N_NODES / 16, 256, 0, stream>>>(T3, rp, col, dinv, b3, Wm, sArr);

  k_gsum<<<nbN, 256, 0, stream>>>(sArr, batch, gsum, cnt);
  k_final<<<1, 512, 0, stream>>>(gsum, cnt, bm, out);
}